// Round 3
// baseline (33498.724 us; speedup 1.0000x reference)
//
#include <hip/hip_runtime.h>

#define NODES    16384
#define EDGES    262144
#define OUT_CH   304      // 64 + 32*3 + 16*9
#define EB       16       // edges per chunk
#define NTHREADS 256

// ---------- workspace layout (ints) ----------
// cnt    : [0, 16384)
// off    : [16384, 32769)      (16385 entries)
// cursor : [32769, 49153)
// eidx   : [65536, 65536+EDGES)
#define WS_CNT    0
#define WS_OFF    16384
#define WS_CURSOR 32769
#define WS_EIDX   65536

// t[c,b] = sum_l rad[l]*P[c,l,b]; racc[e] += sum_b t*feat[e][b]   (scalar feature)
template<int B, int NE>
__device__ __forceinline__ void contract_s(const float* __restrict__ Pp,
    const float (*rad_r)[8], const float* const* feat, float* racc)
{
    for (int b0 = 0; b0 < B; b0 += 4) {
        float4 p[8];
        #pragma unroll
        for (int l = 0; l < 8; ++l)
            p[l] = *reinterpret_cast<const float4*>(Pp + l*B + b0);
        #pragma unroll
        for (int e = 0; e < NE; ++e) {
            float t0 = 0.f, t1 = 0.f, t2 = 0.f, t3 = 0.f;
            #pragma unroll
            for (int l = 0; l < 8; ++l) {
                float r = rad_r[e][l];
                t0 = fmaf(r, p[l].x, t0);
                t1 = fmaf(r, p[l].y, t1);
                t2 = fmaf(r, p[l].z, t2);
                t3 = fmaf(r, p[l].w, t3);
            }
            const float* f = feat[e] + b0;
            racc[e] = fmaf(t0, f[0], racc[e]);
            racc[e] = fmaf(t1, f[1], racc[e]);
            racc[e] = fmaf(t2, f[2], racc[e]);
            racc[e] = fmaf(t3, f[3], racc[e]);
        }
    }
}

// vector (3-component) feature, feat layout [b][3]
template<int B, int NE>
__device__ __forceinline__ void contract_v3(const float* __restrict__ Pp,
    const float (*rad_r)[8], const float* const* feat, float (*racc)[3])
{
    for (int b0 = 0; b0 < B; b0 += 4) {
        float4 p[8];
        #pragma unroll
        for (int l = 0; l < 8; ++l)
            p[l] = *reinterpret_cast<const float4*>(Pp + l*B + b0);
        #pragma unroll
        for (int e = 0; e < NE; ++e) {
            float tv[4] = {0.f, 0.f, 0.f, 0.f};
            #pragma unroll
            for (int l = 0; l < 8; ++l) {
                float r = rad_r[e][l];
                tv[0] = fmaf(r, p[l].x, tv[0]);
                tv[1] = fmaf(r, p[l].y, tv[1]);
                tv[2] = fmaf(r, p[l].z, tv[2]);
                tv[3] = fmaf(r, p[l].w, tv[3]);
            }
            #pragma unroll
            for (int bb = 0; bb < 4; ++bb) {
                const float* f = feat[e] + (b0+bb)*3;
                racc[e][0] = fmaf(tv[bb], f[0], racc[e][0]);
                racc[e][1] = fmaf(tv[bb], f[1], racc[e][1]);
                racc[e][2] = fmaf(tv[bb], f[2], racc[e][2]);
            }
        }
    }
}

// 9-component feature, feat layout [b][9]
template<int B, int NE>
__device__ __forceinline__ void contract_v9(const float* __restrict__ Pp,
    const float (*rad_r)[8], const float* const* feat, float (*racc)[9])
{
    for (int b0 = 0; b0 < B; b0 += 4) {
        float4 p[8];
        #pragma unroll
        for (int l = 0; l < 8; ++l)
            p[l] = *reinterpret_cast<const float4*>(Pp + l*B + b0);
        #pragma unroll
        for (int e = 0; e < NE; ++e) {
            float tv[4] = {0.f, 0.f, 0.f, 0.f};
            #pragma unroll
            for (int l = 0; l < 8; ++l) {
                float r = rad_r[e][l];
                tv[0] = fmaf(r, p[l].x, tv[0]);
                tv[1] = fmaf(r, p[l].y, tv[1]);
                tv[2] = fmaf(r, p[l].z, tv[2]);
                tv[3] = fmaf(r, p[l].w, tv[3]);
            }
            #pragma unroll
            for (int bb = 0; bb < 4; ++bb) {
                const float* f = feat[e] + (b0+bb)*9;
                #pragma unroll
                for (int k = 0; k < 9; ++k)
                    racc[e][k] = fmaf(tv[bb], f[k], racc[e][k]);
            }
        }
    }
}

// ---------------- CSR construction ----------------
__global__ __launch_bounds__(256) void count_kernel(const int* __restrict__ dst,
                                                    int* __restrict__ cnt)
{
    int e = blockIdx.x*256 + threadIdx.x;
    if (e < EDGES) atomicAdd(&cnt[dst[e]], 1);
}

__global__ __launch_bounds__(256) void scan_kernel(const int* __restrict__ cnt,
                                                   int* __restrict__ off,
                                                   int* __restrict__ cursor)
{
    __shared__ int s_part[256];
    const int t = threadIdx.x;
    const int base = t * 64;           // 256 threads x 64 = 16384
    int sum = 0;
    #pragma unroll 4
    for (int i = 0; i < 64; ++i) sum += cnt[base + i];
    s_part[t] = sum;
    __syncthreads();
    // Hillis-Steele inclusive scan over 256 partials
    for (int d = 1; d < 256; d <<= 1) {
        int add = (t >= d) ? s_part[t - d] : 0;
        __syncthreads();
        s_part[t] += add;
        __syncthreads();
    }
    int run = s_part[t] - sum;         // exclusive base for this thread's span
    for (int i = 0; i < 64; ++i) {
        int c = cnt[base + i];
        off[base + i]    = run;
        cursor[base + i] = run;
        run += c;
    }
    if (t == 255) off[NODES] = run;    // == EDGES
}

__global__ __launch_bounds__(256) void scatter_kernel(const int* __restrict__ dst,
                                                      int* __restrict__ cursor,
                                                      int* __restrict__ eidx)
{
    int e = blockIdx.x*256 + threadIdx.x;
    if (e < EDGES) {
        int pos = atomicAdd(&cursor[dst[e]], 1);
        eidx[pos] = e;
    }
}

// ---------------- main node-centric kernel ----------------
__global__ __launch_bounds__(NTHREADS, 2) void node_kernel(
    const float* __restrict__ xa_g, const float* __restrict__ xv_g, const float* __restrict__ xd_g,
    const float* __restrict__ rij_g,
    const float* __restrict__ P000, const float* __restrict__ P110, const float* __restrict__ P220,
    const float* __restrict__ P011, const float* __restrict__ P101, const float* __restrict__ P121,
    const float* __restrict__ P211, const float* __restrict__ P111,
    const float* __restrict__ P022, const float* __restrict__ P112, const float* __restrict__ P202,
    const float* __restrict__ P222, const float* __restrict__ P212,
    const int* __restrict__ src,
    const int* __restrict__ off, const int* __restrict__ eidx,
    float* __restrict__ out)
{
    __shared__ float s_rad[EB][8];
    __shared__ float s_rh[EB][4];
    __shared__ float s_xa[EB][64];
    __shared__ float s_sv[EB][32];
    __shared__ float s_sd[EB][16];
    __shared__ float s_xv[EB][32][3];
    __shared__ float s_uv[EB][16][3];
    __shared__ float s_wd[EB][16][3];
    __shared__ float s_cr[EB][32][3];
    __shared__ float s_xd[EB][16][9];
    __shared__ float s_m[EB][OUT_CH];
    __shared__ float s_nacc[OUT_CH];
    __shared__ int   s_srcn[EB];

    const int t = threadIdx.x;
    const int node = blockIdx.x;
    const int start = off[node];
    const int end   = off[node + 1];

    // zero node accumulator
    for (int ch = t; ch < OUT_CH; ch += NTHREADS) s_nacc[ch] = 0.0f;
    __syncthreads();

    for (int cs = start; cs < end; cs += EB) {
        const int nv = min(EB, end - cs);

        // ---- phase 1a: per-edge radial basis + rh (16 lanes) ----
        if (t < EB) {
            if (t < nv) {
                const int e = eidx[cs + t];
                float r0 = rij_g[e*3+0];
                float r1 = rij_g[e*3+1];
                float r2 = rij_g[e*3+2];
                float x_sq = (r0*r0 + r1*r1 + r2*r2) * 0.125f;   // /R0, R0=8
                float q  = sqrtf(x_sq);
                float w  = fmaxf(1.0f - x_sq, 0.0f);
                const float PI = 3.14159265358979323846f;
                #pragma unroll
                for (int n = 0; n < 8; ++n)
                    s_rad[t][n] = cosf(PI * (float)n * q) * w;
                float y0 = r0*0.875f, y1 = r1*0.875f, y2 = r2*0.875f;  // * 7/R0
                float nn = sqrtf(y0*y0 + y1*y1 + y2*y2);
                float sc = tanhf(nn) / fmaxf(nn, 1e-6f);
                s_rh[t][0] = y0*sc; s_rh[t][1] = y1*sc; s_rh[t][2] = y2*sc; s_rh[t][3] = 0.f;
                s_srcn[t] = src[e];
            } else {
                // padding slot: rad = rh = 0 makes every message term vanish
                #pragma unroll
                for (int n = 0; n < 8; ++n) s_rad[t][n] = 0.0f;
                s_rh[t][0] = 0.f; s_rh[t][1] = 0.f; s_rh[t][2] = 0.f; s_rh[t][3] = 0.f;
                s_srcn[t] = node;   // any valid node; results are zero anyway
            }
        }
        __syncthreads();

        // ---- phase 1b: gather node features, derived per-edge features ----
        {
            const int el  = t >> 4;
            const int sub = t & 15;
            const int n   = s_srcn[el];
            const float rh0 = s_rh[el][0], rh1 = s_rh[el][1], rh2 = s_rh[el][2];
            #pragma unroll
            for (int k = 0; k < 4; ++k) {
                int b = sub + 16*k;
                s_xa[el][b] = xa_g[n*64 + b];
            }
            #pragma unroll
            for (int k = 0; k < 2; ++k) {
                int b = sub + 16*k;
                float v0 = xv_g[(n*32 + b)*3 + 0];
                float v1 = xv_g[(n*32 + b)*3 + 1];
                float v2 = xv_g[(n*32 + b)*3 + 2];
                s_xv[el][b][0] = v0; s_xv[el][b][1] = v1; s_xv[el][b][2] = v2;
                s_sv[el][b] = rh0*v0 + rh1*v1 + rh2*v2;
                s_cr[el][b][0] = rh1*v2 - rh2*v1;
                s_cr[el][b][1] = rh2*v0 - rh0*v2;
                s_cr[el][b][2] = rh0*v1 - rh1*v0;
            }
            {
                int b = sub;
                float d[9];
                #pragma unroll
                for (int k = 0; k < 9; ++k) {
                    d[k] = xd_g[(n*16 + b)*9 + k];
                    s_xd[el][b][k] = d[k];
                }
                float uv0 = d[0]*rh0 + d[1]*rh1 + d[2]*rh2;
                float uv1 = d[3]*rh0 + d[4]*rh1 + d[5]*rh2;
                float uv2 = d[6]*rh0 + d[7]*rh1 + d[8]*rh2;
                s_uv[el][b][0] = uv0; s_uv[el][b][1] = uv1; s_uv[el][b][2] = uv2;
                s_wd[el][b][0] = rh0*d[0] + rh1*d[3] + rh2*d[6];
                s_wd[el][b][1] = rh0*d[1] + rh1*d[4] + rh2*d[7];
                s_wd[el][b][2] = rh0*d[2] + rh1*d[5] + rh2*d[8];
                s_sd[el][b] = rh0*uv0 + rh1*uv1 + rh2*uv2;
            }
        }
        __syncthreads();

        // ---- pass A: m_a (c in [0,64), 4 edge-groups x 4 edges) ----
        {
            const int c  = t & 63;
            const int eg = t >> 6;
            const int el0 = eg*4;
            float rad_r[4][8];
            #pragma unroll
            for (int e4 = 0; e4 < 4; ++e4)
                #pragma unroll
                for (int l = 0; l < 8; ++l) rad_r[e4][l] = s_rad[el0+e4][l];
            float racc[4] = {0,0,0,0};
            const float* f[4];
            f[0]=&s_xa[el0][0]; f[1]=&s_xa[el0+1][0]; f[2]=&s_xa[el0+2][0]; f[3]=&s_xa[el0+3][0];
            contract_s<64,4>(P000 + c*(8*64), rad_r, f, racc);
            f[0]=&s_sv[el0][0]; f[1]=&s_sv[el0+1][0]; f[2]=&s_sv[el0+2][0]; f[3]=&s_sv[el0+3][0];
            contract_s<32,4>(P110 + c*(8*32), rad_r, f, racc);
            f[0]=&s_sd[el0][0]; f[1]=&s_sd[el0+1][0]; f[2]=&s_sd[el0+2][0]; f[3]=&s_sd[el0+3][0];
            contract_s<16,4>(P220 + c*(8*16), rad_r, f, racc);
            #pragma unroll
            for (int e4 = 0; e4 < 4; ++e4)
                s_m[el0+e4][c] = racc[e4];
        }

        // ---- pass V: m_v (c in [0,32), 8 edge-groups x 2 edges) ----
        {
            const int c  = t & 31;
            const int eg = t >> 5;
            const int el0 = eg*2;
            float rad_r[2][8];
            #pragma unroll
            for (int e2 = 0; e2 < 2; ++e2)
                #pragma unroll
                for (int l = 0; l < 8; ++l) rad_r[e2][l] = s_rad[el0+e2][l];
            float accv[2][3] = {{0,0,0},{0,0,0}};
            float accs[2] = {0,0};
            const float* fv[2]; const float* fs[2];
            fv[0]=&s_xv[el0][0][0]; fv[1]=&s_xv[el0+1][0][0];
            contract_v3<32,2>(P011 + c*(8*32), rad_r, fv, accv);
            fv[0]=&s_uv[el0][0][0]; fv[1]=&s_uv[el0+1][0][0];
            contract_v3<16,2>(P121 + c*(8*16), rad_r, fv, accv);
            fv[0]=&s_cr[el0][0][0]; fv[1]=&s_cr[el0+1][0][0];
            contract_v3<32,2>(P111 + c*(8*32), rad_r, fv, accv);
            fs[0]=&s_xa[el0][0]; fs[1]=&s_xa[el0+1][0];
            contract_s<64,2>(P101 + c*(8*64), rad_r, fs, accs);
            fs[0]=&s_sv[el0][0]; fs[1]=&s_sv[el0+1][0];
            contract_s<32,2>(P211 + c*(8*32), rad_r, fs, accs);
            #pragma unroll
            for (int e2 = 0; e2 < 2; ++e2) {
                const int el = el0 + e2;
                #pragma unroll
                for (int i = 0; i < 3; ++i)
                    s_m[el][64 + c*3 + i] = accv[e2][i] + s_rh[el][i]*accs[e2];
            }
        }

        // ---- pass D: m_d (c in [0,16), 16 edge-groups x 1 edge) ----
        {
            const int c  = t & 15;
            const int el = t >> 4;
            float rad_r[1][8];
            #pragma unroll
            for (int l = 0; l < 8; ++l) rad_r[0][l] = s_rad[el][l];
            float accd[1][9] = {{0,0,0,0,0,0,0,0,0}};
            float accj[1][3] = {{0,0,0}};
            float acc0[1] = {0};
            const float* f1[1];
            f1[0] = &s_xd[el][0][0];
            contract_v9<16,1>(P022 + c*(8*16), rad_r, f1, accd);
            f1[0] = &s_xv[el][0][0];
            contract_v3<32,1>(P112 + c*(8*32), rad_r, f1, accj);
            f1[0] = &s_wd[el][0][0];
            contract_v3<16,1>(P222 + c*(8*16), rad_r, f1, accj);
            f1[0] = &s_cr[el][0][0];
            contract_v3<32,1>(P212 + c*(8*32), rad_r, f1, accj);
            f1[0] = &s_xa[el][0];
            contract_s<64,1>(P202 + c*(8*64), rad_r, f1, acc0);
            const float rhv[3] = { s_rh[el][0], s_rh[el][1], s_rh[el][2] };
            #pragma unroll
            for (int i = 0; i < 3; ++i)
                #pragma unroll
                for (int j = 0; j < 3; ++j)
                    s_m[el][160 + c*9 + i*3 + j] =
                        accd[0][i*3+j] + rhv[i]*(accj[0][j] + rhv[j]*acc0[0]);
        }
        __syncthreads();

        // ---- reduce this chunk's 16 edge messages into the node accumulator ----
        for (int ch = t; ch < OUT_CH; ch += NTHREADS) {
            float s = 0.0f;
            #pragma unroll
            for (int el = 0; el < EB; ++el) s += s_m[el][ch];
            s_nacc[ch] += s;
        }
        __syncthreads();
    }

    // ---- single coalesced write per node (no atomics, no output memset) ----
    for (int ch = t; ch < OUT_CH; ch += NTHREADS)
        out[(size_t)node * OUT_CH + ch] = s_nacc[ch];
}

extern "C" void kernel_launch(void* const* d_in, const int* in_sizes, int n_in,
                              void* d_out, int out_size, void* d_ws, size_t ws_size,
                              hipStream_t stream)
{
    const float* xa  = (const float*)d_in[0];
    const float* xv  = (const float*)d_in[1];
    const float* xd  = (const float*)d_in[2];
    const float* rij = (const float*)d_in[3];
    const float* P000 = (const float*)d_in[4];
    const float* P110 = (const float*)d_in[5];
    const float* P220 = (const float*)d_in[6];
    const float* P011 = (const float*)d_in[7];
    const float* P101 = (const float*)d_in[8];
    const float* P121 = (const float*)d_in[9];
    const float* P211 = (const float*)d_in[10];
    const float* P111 = (const float*)d_in[11];
    const float* P022 = (const float*)d_in[12];
    const float* P112 = (const float*)d_in[13];
    const float* P202 = (const float*)d_in[14];
    const float* P222 = (const float*)d_in[15];
    const float* P212 = (const float*)d_in[16];
    const int* src = (const int*)d_in[17];
    const int* dst = (const int*)d_in[18];

    int* ws     = (int*)d_ws;
    int* cnt    = ws + WS_CNT;
    int* off    = ws + WS_OFF;
    int* cursor = ws + WS_CURSOR;
    int* eidx   = ws + WS_EIDX;

    // zero the histogram (ws is re-poisoned to 0xAA before every launch)
    hipMemsetAsync(cnt, 0, NODES * sizeof(int), stream);

    count_kernel  <<<EDGES/256, 256, 0, stream>>>(dst, cnt);
    scan_kernel   <<<1,         256, 0, stream>>>(cnt, off, cursor);
    scatter_kernel<<<EDGES/256, 256, 0, stream>>>(dst, cursor, eidx);

    node_kernel<<<NODES, NTHREADS, 0, stream>>>(
        xa, xv, xd, rij,
        P000, P110, P220, P011, P101, P121, P211, P111,
        P022, P112, P202, P222, P212,
        src, off, eidx, (float*)d_out);
}

// Round 4
// 13995.554 us; speedup vs baseline: 2.3935x; 2.3935x over previous
//
#include <hip/hip_runtime.h>

#define NODES    16384
#define EDGES    262144
#define OUT_CH   304      // 64 + 32*3 + 16*9
#define EB       16       // edges per block
#define NTHREADS 256

// ---------- workspace layout ----------
// msg   : float [EDGES][OUT_CH]                      (offset 0, 318,767,104 B)
// cnt   : int   [NODES]
// off   : int   [NODES+1]
// cursor: int   [NODES]
// eidx  : int   [EDGES]
#define MSG_FLOATS ((size_t)EDGES * OUT_CH)
#define WS_INTS_OFF MSG_FLOATS                 // int region starts here (in 4B units)
#define WS_NEEDED_BYTES ((MSG_FLOATS + NODES + (NODES+1) + NODES + EDGES + 64) * 4)

// t[c,b] = sum_l rad[l]*P[c,l,b]; racc[e] += sum_b t*feat[e][b]   (scalar feature)
template<int B, int NE>
__device__ __forceinline__ void contract_s(const float* __restrict__ Pp,
    const float (*rad_r)[8], const float* const* feat, float* racc)
{
    for (int b0 = 0; b0 < B; b0 += 4) {
        float4 p[8];
        #pragma unroll
        for (int l = 0; l < 8; ++l)
            p[l] = *reinterpret_cast<const float4*>(Pp + l*B + b0);
        #pragma unroll
        for (int e = 0; e < NE; ++e) {
            float t0 = 0.f, t1 = 0.f, t2 = 0.f, t3 = 0.f;
            #pragma unroll
            for (int l = 0; l < 8; ++l) {
                float r = rad_r[e][l];
                t0 = fmaf(r, p[l].x, t0);
                t1 = fmaf(r, p[l].y, t1);
                t2 = fmaf(r, p[l].z, t2);
                t3 = fmaf(r, p[l].w, t3);
            }
            const float* f = feat[e] + b0;
            racc[e] = fmaf(t0, f[0], racc[e]);
            racc[e] = fmaf(t1, f[1], racc[e]);
            racc[e] = fmaf(t2, f[2], racc[e]);
            racc[e] = fmaf(t3, f[3], racc[e]);
        }
    }
}

// vector (3-component) feature, feat layout [b][3]
template<int B, int NE>
__device__ __forceinline__ void contract_v3(const float* __restrict__ Pp,
    const float (*rad_r)[8], const float* const* feat, float (*racc)[3])
{
    for (int b0 = 0; b0 < B; b0 += 4) {
        float4 p[8];
        #pragma unroll
        for (int l = 0; l < 8; ++l)
            p[l] = *reinterpret_cast<const float4*>(Pp + l*B + b0);
        #pragma unroll
        for (int e = 0; e < NE; ++e) {
            float tv[4] = {0.f, 0.f, 0.f, 0.f};
            #pragma unroll
            for (int l = 0; l < 8; ++l) {
                float r = rad_r[e][l];
                tv[0] = fmaf(r, p[l].x, tv[0]);
                tv[1] = fmaf(r, p[l].y, tv[1]);
                tv[2] = fmaf(r, p[l].z, tv[2]);
                tv[3] = fmaf(r, p[l].w, tv[3]);
            }
            #pragma unroll
            for (int bb = 0; bb < 4; ++bb) {
                const float* f = feat[e] + (b0+bb)*3;
                racc[e][0] = fmaf(tv[bb], f[0], racc[e][0]);
                racc[e][1] = fmaf(tv[bb], f[1], racc[e][1]);
                racc[e][2] = fmaf(tv[bb], f[2], racc[e][2]);
            }
        }
    }
}

// 9-component feature, feat layout [b][9]
template<int B, int NE>
__device__ __forceinline__ void contract_v9(const float* __restrict__ Pp,
    const float (*rad_r)[8], const float* const* feat, float (*racc)[9])
{
    for (int b0 = 0; b0 < B; b0 += 4) {
        float4 p[8];
        #pragma unroll
        for (int l = 0; l < 8; ++l)
            p[l] = *reinterpret_cast<const float4*>(Pp + l*B + b0);
        #pragma unroll
        for (int e = 0; e < NE; ++e) {
            float tv[4] = {0.f, 0.f, 0.f, 0.f};
            #pragma unroll
            for (int l = 0; l < 8; ++l) {
                float r = rad_r[e][l];
                tv[0] = fmaf(r, p[l].x, tv[0]);
                tv[1] = fmaf(r, p[l].y, tv[1]);
                tv[2] = fmaf(r, p[l].z, tv[2]);
                tv[3] = fmaf(r, p[l].w, tv[3]);
            }
            #pragma unroll
            for (int bb = 0; bb < 4; ++bb) {
                const float* f = feat[e] + (b0+bb)*9;
                #pragma unroll
                for (int k = 0; k < 9; ++k)
                    racc[e][k] = fmaf(tv[bb], f[k], racc[e][k]);
            }
        }
    }
}

// ---------------- CSR construction (verified in round 3) ----------------
__global__ __launch_bounds__(256) void count_kernel(const int* __restrict__ dst,
                                                    int* __restrict__ cnt)
{
    int e = blockIdx.x*256 + threadIdx.x;
    if (e < EDGES) atomicAdd(&cnt[dst[e]], 1);
}

__global__ __launch_bounds__(256) void scan_kernel(const int* __restrict__ cnt,
                                                   int* __restrict__ off,
                                                   int* __restrict__ cursor)
{
    __shared__ int s_part[256];
    const int t = threadIdx.x;
    const int base = t * 64;           // 256 threads x 64 = 16384
    int sum = 0;
    #pragma unroll 4
    for (int i = 0; i < 64; ++i) sum += cnt[base + i];
    s_part[t] = sum;
    __syncthreads();
    for (int d = 1; d < 256; d <<= 1) {
        int add = (t >= d) ? s_part[t - d] : 0;
        __syncthreads();
        s_part[t] += add;
        __syncthreads();
    }
    int run = s_part[t] - sum;         // exclusive base for this thread's span
    for (int i = 0; i < 64; ++i) {
        int c = cnt[base + i];
        off[base + i]    = run;
        cursor[base + i] = run;
        run += c;
    }
    if (t == 255) off[NODES] = run;    // == EDGES
}

__global__ __launch_bounds__(256) void scatter_kernel(const int* __restrict__ dst,
                                                      int* __restrict__ cursor,
                                                      int* __restrict__ eidx)
{
    int e = blockIdx.x*256 + threadIdx.x;
    if (e < EDGES) {
        int pos = atomicAdd(&cursor[dst[e]], 1);
        eidx[pos] = e;
    }
}

// ---------------- edge kernel: round-2 structure, message store or atomic ----------------
template<bool ATOMIC>
__global__ __launch_bounds__(NTHREADS, 2) void edge_kernel(
    const float* __restrict__ xa_g, const float* __restrict__ xv_g, const float* __restrict__ xd_g,
    const float* __restrict__ rij_g,
    const float* __restrict__ P000, const float* __restrict__ P110, const float* __restrict__ P220,
    const float* __restrict__ P011, const float* __restrict__ P101, const float* __restrict__ P121,
    const float* __restrict__ P211, const float* __restrict__ P111,
    const float* __restrict__ P022, const float* __restrict__ P112, const float* __restrict__ P202,
    const float* __restrict__ P222, const float* __restrict__ P212,
    const int* __restrict__ src, const int* __restrict__ dst,
    float* __restrict__ sink)   // ATOMIC ? out accumulator : msg[E][OUT_CH]
{
    __shared__ float s_rad[EB][8];
    __shared__ float s_rh[EB][4];
    __shared__ float s_xa[EB][64];
    __shared__ float s_sv[EB][32];
    __shared__ float s_sd[EB][16];
    __shared__ float s_xv[EB][32][3];
    __shared__ float s_uv[EB][16][3];
    __shared__ float s_wd[EB][16][3];
    __shared__ float s_cr[EB][32][3];
    __shared__ float s_xd[EB][16][9];
    __shared__ float s_m[EB][OUT_CH];
    __shared__ int   s_dst[EB];
    __shared__ int   s_srcn[EB];

    const int t  = threadIdx.x;
    const int e0 = blockIdx.x * EB;

    // ---- phase 1a: per-edge radial basis + rh (16 lanes) ----
    if (t < EB) {
        const int e = e0 + t;
        float r0 = rij_g[e*3+0];
        float r1 = rij_g[e*3+1];
        float r2 = rij_g[e*3+2];
        float x_sq = (r0*r0 + r1*r1 + r2*r2) * 0.125f;   // /R0, R0=8
        float q  = sqrtf(x_sq);
        float w  = fmaxf(1.0f - x_sq, 0.0f);
        const float PI = 3.14159265358979323846f;
        #pragma unroll
        for (int n = 0; n < 8; ++n)
            s_rad[t][n] = cosf(PI * (float)n * q) * w;
        float y0 = r0*0.875f, y1 = r1*0.875f, y2 = r2*0.875f;  // * 7/R0
        float nn = sqrtf(y0*y0 + y1*y1 + y2*y2);
        float sc = tanhf(nn) / fmaxf(nn, 1e-6f);
        s_rh[t][0] = y0*sc; s_rh[t][1] = y1*sc; s_rh[t][2] = y2*sc; s_rh[t][3] = 0.f;
        s_dst[t]  = dst[e];
        s_srcn[t] = src[e];
    }
    // zero message accumulators
    for (int idx = t; idx < EB*OUT_CH; idx += NTHREADS)
        (&s_m[0][0])[idx] = 0.0f;
    __syncthreads();

    // ---- phase 1b: gather node features, derived per-edge features ----
    {
        const int el  = t >> 4;
        const int sub = t & 15;
        const int n   = s_srcn[el];
        const float rh0 = s_rh[el][0], rh1 = s_rh[el][1], rh2 = s_rh[el][2];
        #pragma unroll
        for (int k = 0; k < 4; ++k) {
            int b = sub + 16*k;
            s_xa[el][b] = xa_g[n*64 + b];
        }
        #pragma unroll
        for (int k = 0; k < 2; ++k) {
            int b = sub + 16*k;
            float v0 = xv_g[(n*32 + b)*3 + 0];
            float v1 = xv_g[(n*32 + b)*3 + 1];
            float v2 = xv_g[(n*32 + b)*3 + 2];
            s_xv[el][b][0] = v0; s_xv[el][b][1] = v1; s_xv[el][b][2] = v2;
            s_sv[el][b] = rh0*v0 + rh1*v1 + rh2*v2;
            s_cr[el][b][0] = rh1*v2 - rh2*v1;
            s_cr[el][b][1] = rh2*v0 - rh0*v2;
            s_cr[el][b][2] = rh0*v1 - rh1*v0;
        }
        {
            int b = sub;
            float d[9];
            #pragma unroll
            for (int k = 0; k < 9; ++k) {
                d[k] = xd_g[(n*16 + b)*9 + k];
                s_xd[el][b][k] = d[k];
            }
            float uv0 = d[0]*rh0 + d[1]*rh1 + d[2]*rh2;
            float uv1 = d[3]*rh0 + d[4]*rh1 + d[5]*rh2;
            float uv2 = d[6]*rh0 + d[7]*rh1 + d[8]*rh2;
            s_uv[el][b][0] = uv0; s_uv[el][b][1] = uv1; s_uv[el][b][2] = uv2;
            s_wd[el][b][0] = rh0*d[0] + rh1*d[3] + rh2*d[6];
            s_wd[el][b][1] = rh0*d[1] + rh1*d[4] + rh2*d[7];
            s_wd[el][b][2] = rh0*d[2] + rh1*d[5] + rh2*d[8];
            s_sd[el][b] = rh0*uv0 + rh1*uv1 + rh2*uv2;
        }
    }
    __syncthreads();

    // ---- pass A: m_a (c in [0,64), 4 edge-groups x 4 edges) ----
    {
        const int c  = t & 63;
        const int eg = t >> 6;
        const int el0 = eg*4;
        float rad_r[4][8];
        #pragma unroll
        for (int e4 = 0; e4 < 4; ++e4)
            #pragma unroll
            for (int l = 0; l < 8; ++l) rad_r[e4][l] = s_rad[el0+e4][l];
        float racc[4] = {0,0,0,0};
        const float* f[4];
        f[0]=&s_xa[el0][0]; f[1]=&s_xa[el0+1][0]; f[2]=&s_xa[el0+2][0]; f[3]=&s_xa[el0+3][0];
        contract_s<64,4>(P000 + c*(8*64), rad_r, f, racc);
        f[0]=&s_sv[el0][0]; f[1]=&s_sv[el0+1][0]; f[2]=&s_sv[el0+2][0]; f[3]=&s_sv[el0+3][0];
        contract_s<32,4>(P110 + c*(8*32), rad_r, f, racc);
        f[0]=&s_sd[el0][0]; f[1]=&s_sd[el0+1][0]; f[2]=&s_sd[el0+2][0]; f[3]=&s_sd[el0+3][0];
        contract_s<16,4>(P220 + c*(8*16), rad_r, f, racc);
        #pragma unroll
        for (int e4 = 0; e4 < 4; ++e4)
            s_m[el0+e4][c] += racc[e4];
    }

    // ---- pass V: m_v (c in [0,32), 8 edge-groups x 2 edges) ----
    {
        const int c  = t & 31;
        const int eg = t >> 5;
        const int el0 = eg*2;
        float rad_r[2][8];
        #pragma unroll
        for (int e2 = 0; e2 < 2; ++e2)
            #pragma unroll
            for (int l = 0; l < 8; ++l) rad_r[e2][l] = s_rad[el0+e2][l];
        float accv[2][3] = {{0,0,0},{0,0,0}};
        float accs[2] = {0,0};
        const float* fv[2]; const float* fs[2];
        fv[0]=&s_xv[el0][0][0]; fv[1]=&s_xv[el0+1][0][0];
        contract_v3<32,2>(P011 + c*(8*32), rad_r, fv, accv);
        fv[0]=&s_uv[el0][0][0]; fv[1]=&s_uv[el0+1][0][0];
        contract_v3<16,2>(P121 + c*(8*16), rad_r, fv, accv);
        fv[0]=&s_cr[el0][0][0]; fv[1]=&s_cr[el0+1][0][0];
        contract_v3<32,2>(P111 + c*(8*32), rad_r, fv, accv);
        fs[0]=&s_xa[el0][0]; fs[1]=&s_xa[el0+1][0];
        contract_s<64,2>(P101 + c*(8*64), rad_r, fs, accs);
        fs[0]=&s_sv[el0][0]; fs[1]=&s_sv[el0+1][0];
        contract_s<32,2>(P211 + c*(8*32), rad_r, fs, accs);
        #pragma unroll
        for (int e2 = 0; e2 < 2; ++e2) {
            const int el = el0 + e2;
            #pragma unroll
            for (int i = 0; i < 3; ++i)
                s_m[el][64 + c*3 + i] += accv[e2][i] + s_rh[el][i]*accs[e2];
        }
    }

    // ---- pass D: m_d (c in [0,16), 16 edge-groups x 1 edge) ----
    {
        const int c  = t & 15;
        const int el = t >> 4;
        float rad_r[1][8];
        #pragma unroll
        for (int l = 0; l < 8; ++l) rad_r[0][l] = s_rad[el][l];
        float accd[1][9] = {{0,0,0,0,0,0,0,0,0}};
        float accj[1][3] = {{0,0,0}};
        float acc0[1] = {0};
        const float* f1[1];
        f1[0] = &s_xd[el][0][0];
        contract_v9<16,1>(P022 + c*(8*16), rad_r, f1, accd);
        f1[0] = &s_xv[el][0][0];
        contract_v3<32,1>(P112 + c*(8*32), rad_r, f1, accj);
        f1[0] = &s_wd[el][0][0];
        contract_v3<16,1>(P222 + c*(8*16), rad_r, f1, accj);
        f1[0] = &s_cr[el][0][0];
        contract_v3<32,1>(P212 + c*(8*32), rad_r, f1, accj);
        f1[0] = &s_xa[el][0];
        contract_s<64,1>(P202 + c*(8*64), rad_r, f1, acc0);
        const float rhv[3] = { s_rh[el][0], s_rh[el][1], s_rh[el][2] };
        #pragma unroll
        for (int i = 0; i < 3; ++i)
            #pragma unroll
            for (int j = 0; j < 3; ++j)
                s_m[el][160 + c*9 + i*3 + j] +=
                    accd[0][i*3+j] + rhv[i]*(accj[0][j] + rhv[j]*acc0[0]);
    }
    __syncthreads();

    // ---- emit: coalesced message store (main path) or atomic scatter (fallback) ----
    for (int idx = t; idx < EB*OUT_CH; idx += NTHREADS) {
        int el = idx / OUT_CH;
        int ch = idx - el*OUT_CH;
        if constexpr (ATOMIC) {
            atomicAdd(&sink[(size_t)s_dst[el]*OUT_CH + ch], s_m[el][ch]);
        } else {
            sink[(size_t)(e0 + el)*OUT_CH + ch] = s_m[el][ch];
        }
    }
}

// ---------------- gather-reduce: one block per node ----------------
__global__ __launch_bounds__(256) void reduce_kernel(
    const float* __restrict__ msg, const int* __restrict__ off,
    const int* __restrict__ eidx, float* __restrict__ out)
{
    const int node = blockIdx.x;
    const int t = threadIdx.x;
    const int start = off[node];
    const int end   = off[node + 1];
    float a0 = 0.0f, a1 = 0.0f;
    for (int k = start; k < end; ++k) {
        const float* row = msg + (size_t)eidx[k] * OUT_CH;
        a0 += row[t];
        if (t < OUT_CH - 256) a1 += row[256 + t];
    }
    float* orow = out + (size_t)node * OUT_CH;
    orow[t] = a0;
    if (t < OUT_CH - 256) orow[256 + t] = a1;
}

extern "C" void kernel_launch(void* const* d_in, const int* in_sizes, int n_in,
                              void* d_out, int out_size, void* d_ws, size_t ws_size,
                              hipStream_t stream)
{
    const float* xa  = (const float*)d_in[0];
    const float* xv  = (const float*)d_in[1];
    const float* xd  = (const float*)d_in[2];
    const float* rij = (const float*)d_in[3];
    const float* P000 = (const float*)d_in[4];
    const float* P110 = (const float*)d_in[5];
    const float* P220 = (const float*)d_in[6];
    const float* P011 = (const float*)d_in[7];
    const float* P101 = (const float*)d_in[8];
    const float* P121 = (const float*)d_in[9];
    const float* P211 = (const float*)d_in[10];
    const float* P111 = (const float*)d_in[11];
    const float* P022 = (const float*)d_in[12];
    const float* P112 = (const float*)d_in[13];
    const float* P202 = (const float*)d_in[14];
    const float* P222 = (const float*)d_in[15];
    const float* P212 = (const float*)d_in[16];
    const int* src = (const int*)d_in[17];
    const int* dst = (const int*)d_in[18];

    if (ws_size >= WS_NEEDED_BYTES) {
        float* msg  = (float*)d_ws;
        int* ip     = (int*)d_ws + WS_INTS_OFF;
        int* cnt    = ip;
        int* off    = ip + NODES;
        int* cursor = ip + NODES + (NODES + 1);
        int* eidx   = ip + NODES + (NODES + 1) + NODES;

        hipMemsetAsync(cnt, 0, NODES * sizeof(int), stream);
        count_kernel  <<<EDGES/256, 256, 0, stream>>>(dst, cnt);
        scan_kernel   <<<1,         256, 0, stream>>>(cnt, off, cursor);
        scatter_kernel<<<EDGES/256, 256, 0, stream>>>(dst, cursor, eidx);

        edge_kernel<false><<<EDGES/EB, NTHREADS, 0, stream>>>(
            xa, xv, xd, rij,
            P000, P110, P220, P011, P101, P121, P211, P111,
            P022, P112, P202, P222, P212,
            src, dst, msg);

        reduce_kernel<<<NODES, 256, 0, stream>>>(msg, off, eidx, (float*)d_out);
    } else {
        // fallback: round-2 atomic path
        hipMemsetAsync(d_out, 0, (size_t)out_size * sizeof(float), stream);
        edge_kernel<true><<<EDGES/EB, NTHREADS, 0, stream>>>(
            xa, xv, xd, rij,
            P000, P110, P220, P011, P101, P121, P211, P111,
            P022, P112, P202, P222, P212,
            src, dst, (float*)d_out);
    }
}

// Round 5
// 13920.184 us; speedup vs baseline: 2.4065x; 1.0054x over previous
//
#include <hip/hip_runtime.h>

#define NODES    16384
#define EDGES    262144
#define OUT_CH   304      // 64 + 32*3 + 16*9
#define EB       16       // edges per block
#define NTHREADS 256

// ---------- workspace layout (ints, ~1.25 MB total) ----------
#define WS_CNT    0
#define WS_OFF    (NODES)                       // 16385 entries
#define WS_CURSOR (NODES + NODES + 1)
#define WS_EIDX   (NODES + NODES + 1 + NODES)

// t[c,b] = sum_l rad[l]*P[c,l,b]; racc[e] += sum_b t*feat[e][b]   (scalar feature)
template<int B, int NE>
__device__ __forceinline__ void contract_s(const float* __restrict__ Pp,
    const float (*rad_r)[8], const float* const* feat, float* racc)
{
    for (int b0 = 0; b0 < B; b0 += 4) {
        float4 p[8];
        #pragma unroll
        for (int l = 0; l < 8; ++l)
            p[l] = *reinterpret_cast<const float4*>(Pp + l*B + b0);
        #pragma unroll
        for (int e = 0; e < NE; ++e) {
            float t0 = 0.f, t1 = 0.f, t2 = 0.f, t3 = 0.f;
            #pragma unroll
            for (int l = 0; l < 8; ++l) {
                float r = rad_r[e][l];
                t0 = fmaf(r, p[l].x, t0);
                t1 = fmaf(r, p[l].y, t1);
                t2 = fmaf(r, p[l].z, t2);
                t3 = fmaf(r, p[l].w, t3);
            }
            const float* f = feat[e] + b0;
            racc[e] = fmaf(t0, f[0], racc[e]);
            racc[e] = fmaf(t1, f[1], racc[e]);
            racc[e] = fmaf(t2, f[2], racc[e]);
            racc[e] = fmaf(t3, f[3], racc[e]);
        }
    }
}

// vector (3-component) feature, feat layout [b][3]
template<int B, int NE>
__device__ __forceinline__ void contract_v3(const float* __restrict__ Pp,
    const float (*rad_r)[8], const float* const* feat, float (*racc)[3])
{
    for (int b0 = 0; b0 < B; b0 += 4) {
        float4 p[8];
        #pragma unroll
        for (int l = 0; l < 8; ++l)
            p[l] = *reinterpret_cast<const float4*>(Pp + l*B + b0);
        #pragma unroll
        for (int e = 0; e < NE; ++e) {
            float tv[4] = {0.f, 0.f, 0.f, 0.f};
            #pragma unroll
            for (int l = 0; l < 8; ++l) {
                float r = rad_r[e][l];
                tv[0] = fmaf(r, p[l].x, tv[0]);
                tv[1] = fmaf(r, p[l].y, tv[1]);
                tv[2] = fmaf(r, p[l].z, tv[2]);
                tv[3] = fmaf(r, p[l].w, tv[3]);
            }
            #pragma unroll
            for (int bb = 0; bb < 4; ++bb) {
                const float* f = feat[e] + (b0+bb)*3;
                racc[e][0] = fmaf(tv[bb], f[0], racc[e][0]);
                racc[e][1] = fmaf(tv[bb], f[1], racc[e][1]);
                racc[e][2] = fmaf(tv[bb], f[2], racc[e][2]);
            }
        }
    }
}

// 9-component feature, feat layout [b][9]
template<int B, int NE>
__device__ __forceinline__ void contract_v9(const float* __restrict__ Pp,
    const float (*rad_r)[8], const float* const* feat, float (*racc)[9])
{
    for (int b0 = 0; b0 < B; b0 += 4) {
        float4 p[8];
        #pragma unroll
        for (int l = 0; l < 8; ++l)
            p[l] = *reinterpret_cast<const float4*>(Pp + l*B + b0);
        #pragma unroll
        for (int e = 0; e < NE; ++e) {
            float tv[4] = {0.f, 0.f, 0.f, 0.f};
            #pragma unroll
            for (int l = 0; l < 8; ++l) {
                float r = rad_r[e][l];
                tv[0] = fmaf(r, p[l].x, tv[0]);
                tv[1] = fmaf(r, p[l].y, tv[1]);
                tv[2] = fmaf(r, p[l].z, tv[2]);
                tv[3] = fmaf(r, p[l].w, tv[3]);
            }
            #pragma unroll
            for (int bb = 0; bb < 4; ++bb) {
                const float* f = feat[e] + (b0+bb)*9;
                #pragma unroll
                for (int k = 0; k < 9; ++k)
                    racc[e][k] = fmaf(tv[bb], f[k], racc[e][k]);
            }
        }
    }
}

// ---------------- CSR construction (verified) ----------------
__global__ __launch_bounds__(256) void count_kernel(const int* __restrict__ dst,
                                                    int* __restrict__ cnt)
{
    int e = blockIdx.x*256 + threadIdx.x;
    if (e < EDGES) atomicAdd(&cnt[dst[e]], 1);
}

__global__ __launch_bounds__(256) void scan_kernel(const int* __restrict__ cnt,
                                                   int* __restrict__ off,
                                                   int* __restrict__ cursor)
{
    __shared__ int s_part[256];
    const int t = threadIdx.x;
    const int base = t * 64;           // 256 threads x 64 = 16384
    int sum = 0;
    #pragma unroll 4
    for (int i = 0; i < 64; ++i) sum += cnt[base + i];
    s_part[t] = sum;
    __syncthreads();
    for (int d = 1; d < 256; d <<= 1) {
        int add = (t >= d) ? s_part[t - d] : 0;
        __syncthreads();
        s_part[t] += add;
        __syncthreads();
    }
    int run = s_part[t] - sum;         // exclusive base for this thread's span
    for (int i = 0; i < 64; ++i) {
        int c = cnt[base + i];
        off[base + i]    = run;
        cursor[base + i] = run;
        run += c;
    }
    if (t == 255) off[NODES] = run;    // == EDGES
}

__global__ __launch_bounds__(256) void scatter_kernel(const int* __restrict__ dst,
                                                      int* __restrict__ cursor,
                                                      int* __restrict__ eidx)
{
    int e = blockIdx.x*256 + threadIdx.x;
    if (e < EDGES) {
        int pos = atomicAdd(&cursor[dst[e]], 1);
        eidx[pos] = e;
    }
}

// ---------------- edge kernel: CSR-ordered, segmented atomic emit ----------------
__global__ __launch_bounds__(NTHREADS, 2) void edge_kernel(
    const float* __restrict__ xa_g, const float* __restrict__ xv_g, const float* __restrict__ xd_g,
    const float* __restrict__ rij_g,
    const float* __restrict__ P000, const float* __restrict__ P110, const float* __restrict__ P220,
    const float* __restrict__ P011, const float* __restrict__ P101, const float* __restrict__ P121,
    const float* __restrict__ P211, const float* __restrict__ P111,
    const float* __restrict__ P022, const float* __restrict__ P112, const float* __restrict__ P202,
    const float* __restrict__ P222, const float* __restrict__ P212,
    const int* __restrict__ src, const int* __restrict__ dst,
    const int* __restrict__ eidx,
    float* __restrict__ out)
{
    __shared__ float s_rad[EB][8];
    __shared__ float s_rh[EB][4];
    __shared__ float s_xa[EB][64];
    __shared__ float s_sv[EB][32];
    __shared__ float s_sd[EB][16];
    __shared__ float s_xv[EB][32][3];
    __shared__ float s_uv[EB][16][3];
    __shared__ float s_wd[EB][16][3];
    __shared__ float s_cr[EB][32][3];
    __shared__ float s_xd[EB][16][9];
    __shared__ float s_m[EB][OUT_CH];
    __shared__ int   s_dst[EB];
    __shared__ int   s_srcn[EB];

    const int t  = threadIdx.x;
    const int e0 = blockIdx.x * EB;     // CSR slot base; EDGES % EB == 0

    // ---- phase 1a: per-edge radial basis + rh (16 lanes) ----
    if (t < EB) {
        const int e = eidx[e0 + t];     // CSR-ordered: s_dst will be non-decreasing
        float r0 = rij_g[e*3+0];
        float r1 = rij_g[e*3+1];
        float r2 = rij_g[e*3+2];
        float x_sq = (r0*r0 + r1*r1 + r2*r2) * 0.125f;   // /R0, R0=8
        float q  = sqrtf(x_sq);
        float w  = fmaxf(1.0f - x_sq, 0.0f);
        const float PI = 3.14159265358979323846f;
        #pragma unroll
        for (int n = 0; n < 8; ++n)
            s_rad[t][n] = cosf(PI * (float)n * q) * w;
        float y0 = r0*0.875f, y1 = r1*0.875f, y2 = r2*0.875f;  // * 7/R0
        float nn = sqrtf(y0*y0 + y1*y1 + y2*y2);
        float sc = tanhf(nn) / fmaxf(nn, 1e-6f);
        s_rh[t][0] = y0*sc; s_rh[t][1] = y1*sc; s_rh[t][2] = y2*sc; s_rh[t][3] = 0.f;
        s_dst[t]  = dst[e];
        s_srcn[t] = src[e];
    }
    // zero message accumulators
    for (int idx = t; idx < EB*OUT_CH; idx += NTHREADS)
        (&s_m[0][0])[idx] = 0.0f;
    __syncthreads();

    // ---- phase 1b: gather node features, derived per-edge features ----
    {
        const int el  = t >> 4;
        const int sub = t & 15;
        const int n   = s_srcn[el];
        const float rh0 = s_rh[el][0], rh1 = s_rh[el][1], rh2 = s_rh[el][2];
        #pragma unroll
        for (int k = 0; k < 4; ++k) {
            int b = sub + 16*k;
            s_xa[el][b] = xa_g[n*64 + b];
        }
        #pragma unroll
        for (int k = 0; k < 2; ++k) {
            int b = sub + 16*k;
            float v0 = xv_g[(n*32 + b)*3 + 0];
            float v1 = xv_g[(n*32 + b)*3 + 1];
            float v2 = xv_g[(n*32 + b)*3 + 2];
            s_xv[el][b][0] = v0; s_xv[el][b][1] = v1; s_xv[el][b][2] = v2;
            s_sv[el][b] = rh0*v0 + rh1*v1 + rh2*v2;
            s_cr[el][b][0] = rh1*v2 - rh2*v1;
            s_cr[el][b][1] = rh2*v0 - rh0*v2;
            s_cr[el][b][2] = rh0*v1 - rh1*v0;
        }
        {
            int b = sub;
            float d[9];
            #pragma unroll
            for (int k = 0; k < 9; ++k) {
                d[k] = xd_g[(n*16 + b)*9 + k];
                s_xd[el][b][k] = d[k];
            }
            float uv0 = d[0]*rh0 + d[1]*rh1 + d[2]*rh2;
            float uv1 = d[3]*rh0 + d[4]*rh1 + d[5]*rh2;
            float uv2 = d[6]*rh0 + d[7]*rh1 + d[8]*rh2;
            s_uv[el][b][0] = uv0; s_uv[el][b][1] = uv1; s_uv[el][b][2] = uv2;
            s_wd[el][b][0] = rh0*d[0] + rh1*d[3] + rh2*d[6];
            s_wd[el][b][1] = rh0*d[1] + rh1*d[4] + rh2*d[7];
            s_wd[el][b][2] = rh0*d[2] + rh1*d[5] + rh2*d[8];
            s_sd[el][b] = rh0*uv0 + rh1*uv1 + rh2*uv2;
        }
    }
    __syncthreads();

    // ---- pass A: m_a (c in [0,64), 4 edge-groups x 4 edges) ----
    {
        const int c  = t & 63;
        const int eg = t >> 6;
        const int el0 = eg*4;
        float rad_r[4][8];
        #pragma unroll
        for (int e4 = 0; e4 < 4; ++e4)
            #pragma unroll
            for (int l = 0; l < 8; ++l) rad_r[e4][l] = s_rad[el0+e4][l];
        float racc[4] = {0,0,0,0};
        const float* f[4];
        f[0]=&s_xa[el0][0]; f[1]=&s_xa[el0+1][0]; f[2]=&s_xa[el0+2][0]; f[3]=&s_xa[el0+3][0];
        contract_s<64,4>(P000 + c*(8*64), rad_r, f, racc);
        f[0]=&s_sv[el0][0]; f[1]=&s_sv[el0+1][0]; f[2]=&s_sv[el0+2][0]; f[3]=&s_sv[el0+3][0];
        contract_s<32,4>(P110 + c*(8*32), rad_r, f, racc);
        f[0]=&s_sd[el0][0]; f[1]=&s_sd[el0+1][0]; f[2]=&s_sd[el0+2][0]; f[3]=&s_sd[el0+3][0];
        contract_s<16,4>(P220 + c*(8*16), rad_r, f, racc);
        #pragma unroll
        for (int e4 = 0; e4 < 4; ++e4)
            s_m[el0+e4][c] += racc[e4];
    }

    // ---- pass V: m_v (c in [0,32), 8 edge-groups x 2 edges) ----
    {
        const int c  = t & 31;
        const int eg = t >> 5;
        const int el0 = eg*2;
        float rad_r[2][8];
        #pragma unroll
        for (int e2 = 0; e2 < 2; ++e2)
            #pragma unroll
            for (int l = 0; l < 8; ++l) rad_r[e2][l] = s_rad[el0+e2][l];
        float accv[2][3] = {{0,0,0},{0,0,0}};
        float accs[2] = {0,0};
        const float* fv[2]; const float* fs[2];
        fv[0]=&s_xv[el0][0][0]; fv[1]=&s_xv[el0+1][0][0];
        contract_v3<32,2>(P011 + c*(8*32), rad_r, fv, accv);
        fv[0]=&s_uv[el0][0][0]; fv[1]=&s_uv[el0+1][0][0];
        contract_v3<16,2>(P121 + c*(8*16), rad_r, fv, accv);
        fv[0]=&s_cr[el0][0][0]; fv[1]=&s_cr[el0+1][0][0];
        contract_v3<32,2>(P111 + c*(8*32), rad_r, fv, accv);
        fs[0]=&s_xa[el0][0]; fs[1]=&s_xa[el0+1][0];
        contract_s<64,2>(P101 + c*(8*64), rad_r, fs, accs);
        fs[0]=&s_sv[el0][0]; fs[1]=&s_sv[el0+1][0];
        contract_s<32,2>(P211 + c*(8*32), rad_r, fs, accs);
        #pragma unroll
        for (int e2 = 0; e2 < 2; ++e2) {
            const int el = el0 + e2;
            #pragma unroll
            for (int i = 0; i < 3; ++i)
                s_m[el][64 + c*3 + i] += accv[e2][i] + s_rh[el][i]*accs[e2];
        }
    }

    // ---- pass D: m_d (c in [0,16), 16 edge-groups x 1 edge) ----
    {
        const int c  = t & 15;
        const int el = t >> 4;
        float rad_r[1][8];
        #pragma unroll
        for (int l = 0; l < 8; ++l) rad_r[0][l] = s_rad[el][l];
        float accd[1][9] = {{0,0,0,0,0,0,0,0,0}};
        float accj[1][3] = {{0,0,0}};
        float acc0[1] = {0};
        const float* f1[1];
        f1[0] = &s_xd[el][0][0];
        contract_v9<16,1>(P022 + c*(8*16), rad_r, f1, accd);
        f1[0] = &s_xv[el][0][0];
        contract_v3<32,1>(P112 + c*(8*32), rad_r, f1, accj);
        f1[0] = &s_wd[el][0][0];
        contract_v3<16,1>(P222 + c*(8*16), rad_r, f1, accj);
        f1[0] = &s_cr[el][0][0];
        contract_v3<32,1>(P212 + c*(8*32), rad_r, f1, accj);
        f1[0] = &s_xa[el][0];
        contract_s<64,1>(P202 + c*(8*64), rad_r, f1, acc0);
        const float rhv[3] = { s_rh[el][0], s_rh[el][1], s_rh[el][2] };
        #pragma unroll
        for (int i = 0; i < 3; ++i)
            #pragma unroll
            for (int j = 0; j < 3; ++j)
                s_m[el][160 + c*9 + i*3 + j] +=
                    accd[0][i*3+j] + rhv[i]*(accj[0][j] + rhv[j]*acc0[0]);
    }
    __syncthreads();

    // ---- segmented emit: s_dst is non-decreasing (CSR order), so reduce runs
    //      of equal dst in-register and emit ONE atomicAdd per (segment, channel).
    for (int ch = t; ch < OUT_CH; ch += NTHREADS) {
        float run = 0.0f;
        #pragma unroll
        for (int el = 0; el < EB; ++el) {
            run += s_m[el][ch];
            if (el == EB-1 || s_dst[el+1] != s_dst[el]) {
                atomicAdd(&out[(size_t)s_dst[el]*OUT_CH + ch], run);
                run = 0.0f;
            }
        }
    }
}

extern "C" void kernel_launch(void* const* d_in, const int* in_sizes, int n_in,
                              void* d_out, int out_size, void* d_ws, size_t ws_size,
                              hipStream_t stream)
{
    const float* xa  = (const float*)d_in[0];
    const float* xv  = (const float*)d_in[1];
    const float* xd  = (const float*)d_in[2];
    const float* rij = (const float*)d_in[3];
    const float* P000 = (const float*)d_in[4];
    const float* P110 = (const float*)d_in[5];
    const float* P220 = (const float*)d_in[6];
    const float* P011 = (const float*)d_in[7];
    const float* P101 = (const float*)d_in[8];
    const float* P121 = (const float*)d_in[9];
    const float* P211 = (const float*)d_in[10];
    const float* P111 = (const float*)d_in[11];
    const float* P022 = (const float*)d_in[12];
    const float* P112 = (const float*)d_in[13];
    const float* P202 = (const float*)d_in[14];
    const float* P222 = (const float*)d_in[15];
    const float* P212 = (const float*)d_in[16];
    const int* src = (const int*)d_in[17];
    const int* dst = (const int*)d_in[18];

    int* ws     = (int*)d_ws;
    int* cnt    = ws + WS_CNT;
    int* off    = ws + WS_OFF;
    int* cursor = ws + WS_CURSOR;
    int* eidx   = ws + WS_EIDX;

    // zero histogram + output accumulator (both re-poisoned before every launch)
    hipMemsetAsync(cnt, 0, NODES * sizeof(int), stream);
    hipMemsetAsync(d_out, 0, (size_t)out_size * sizeof(float), stream);

    count_kernel  <<<EDGES/256, 256, 0, stream>>>(dst, cnt);
    scan_kernel   <<<1,         256, 0, stream>>>(cnt, off, cursor);
    scatter_kernel<<<EDGES/256, 256, 0, stream>>>(dst, cursor, eidx);

    edge_kernel<<<EDGES/EB, NTHREADS, 0, stream>>>(
        xa, xv, xd, rij,
        P000, P110, P220, P011, P101, P121, P211, P111,
        P022, P112, P202, P222, P212,
        src, dst, eidx, (float*)d_out);
}

// Round 6
// 2346.448 us; speedup vs baseline: 14.2764x; 5.9324x over previous
//
#include <hip/hip_runtime.h>

#define NODES    16384
#define EDGES    262144
#define OUT_CH   304      // 64 + 32*3 + 16*9
#define EB       16       // edges per block
#define NTHREADS 256

// ---------- packed-P workspace layout (floats) ----------
// PA  [l8][bq28][c64][4] : {P000,P110,P220}  -> 57344
// PVv [l8][bq24][c32][4] : {P011,P121,P111,0}-> 24576
// PVs [l8][bq24][c32][4] : {P101,P211}       -> 24576
// PDd [l8][bq4 ][c16][4] : {P022}            -> 2048
// PDv [l8][bq24][c16][4] : {P112,0,P212,P222}-> 12288
// PDs [l8][bq16][c16][4] : {P202}            -> 8192
#define OFF_PA   0
#define OFF_PVV  57344
#define OFF_PVS  81920
#define OFF_PDD  106496
#define OFF_PDV  108544
#define OFF_PDS  120832
#define PACK_TOTAL 129024

// ---------- macros: all-register inner loops, no arrays ----------
#define FMA4(tv,qv,r) tv.x=fmaf(qv.x,(r),tv.x); tv.y=fmaf(qv.y,(r),tv.y); \
                      tv.z=fmaf(qv.z,(r),tv.z); tv.w=fmaf(qv.w,(r),tv.w)
#define DOT4(acc,tv,fv) acc=fmaf(tv.x,fv.x,fmaf(tv.y,fv.y,fmaf(tv.z,fv.z,fmaf(tv.w,fv.w,acc))))
#define RADROW(p, el) const float p##0=s_rad[el][0], p##1=s_rad[el][1], p##2=s_rad[el][2], \
  p##3=s_rad[el][3], p##4=s_rad[el][4], p##5=s_rad[el][5], p##6=s_rad[el][6], p##7=s_rad[el][7]
#define LOADQ8(P4, NQ, CW) \
  const float4 q0=(P4)[(0*(NQ)+bq)*(CW)], q1=(P4)[(1*(NQ)+bq)*(CW)], \
               q2=(P4)[(2*(NQ)+bq)*(CW)], q3=(P4)[(3*(NQ)+bq)*(CW)], \
               q4=(P4)[(4*(NQ)+bq)*(CW)], q5=(P4)[(5*(NQ)+bq)*(CW)], \
               q6=(P4)[(6*(NQ)+bq)*(CW)], q7=(P4)[(7*(NQ)+bq)*(CW)]
#define TCOMP(tv,p) float4 tv={0.f,0.f,0.f,0.f}; FMA4(tv,q0,p##0); FMA4(tv,q1,p##1); \
  FMA4(tv,q2,p##2); FMA4(tv,q3,p##3); FMA4(tv,q4,p##4); FMA4(tv,q5,p##5); \
  FMA4(tv,q6,p##6); FMA4(tv,q7,p##7)

// ---------------- P prepack (one-time per launch, ~0.5 MB) ----------------
__global__ __launch_bounds__(256) void pack_kernel(
    const float* __restrict__ P000, const float* __restrict__ P110, const float* __restrict__ P220,
    const float* __restrict__ P011, const float* __restrict__ P101, const float* __restrict__ P121,
    const float* __restrict__ P211, const float* __restrict__ P111,
    const float* __restrict__ P022, const float* __restrict__ P112, const float* __restrict__ P202,
    const float* __restrict__ P222, const float* __restrict__ P212,
    float* __restrict__ W)
{
    int idx = blockIdx.x*256 + threadIdx.x;
    if (idx >= PACK_TOTAL) return;
    float v = 0.0f;
    int o = idx;
    if (o < OFF_PVV) {                       // PA: C=64, NQ=28
        int j=o&3, c=(o>>2)&63, rem=o>>8, bq=rem%28, l=rem/28, b=bq*4+j;
        if      (b <  64) v = P000[(c*8+l)*64 + b];
        else if (b <  96) v = P110[(c*8+l)*32 + (b-64)];
        else              v = P220[(c*8+l)*16 + (b-96)];
    } else if (o < OFF_PVS) {                // PVv: C=32, NQ=24
        o -= OFF_PVV;
        int j=o&3, c=(o>>2)&31, rem=o>>7, bq=rem%24, l=rem/24, b=bq*4+j;
        if      (b <  32) v = P011[(c*8+l)*32 + b];
        else if (b <  48) v = P121[(c*8+l)*16 + (b-32)];
        else if (b <  80) v = P111[(c*8+l)*32 + (b-48)];
        else              v = 0.0f;          // wd range unused by V
    } else if (o < OFF_PDD) {                // PVs: C=32, NQ=24
        o -= OFF_PVS;
        int j=o&3, c=(o>>2)&31, rem=o>>7, bq=rem%24, l=rem/24, b=bq*4+j;
        if (b < 64) v = P101[(c*8+l)*64 + b];
        else        v = P211[(c*8+l)*32 + (b-64)];
    } else if (o < OFF_PDV) {                // PDd: C=16, NQ=4
        o -= OFF_PDD;
        int j=o&3, c=(o>>2)&15, rem=o>>6, bq=rem%4, l=rem/4, b=bq*4+j;
        v = P022[(c*8+l)*16 + b];
    } else if (o < OFF_PDS) {                // PDv: C=16, NQ=24
        o -= OFF_PDV;
        int j=o&3, c=(o>>2)&15, rem=o>>6, bq=rem%24, l=rem/24, b=bq*4+j;
        if      (b <  32) v = P112[(c*8+l)*32 + b];
        else if (b <  48) v = 0.0f;          // uv range unused by D
        else if (b <  80) v = P212[(c*8+l)*32 + (b-48)];
        else              v = P222[(c*8+l)*16 + (b-80)];
    } else {                                 // PDs: C=16, NQ=16
        o -= OFF_PDS;
        int j=o&3, c=(o>>2)&15, rem=o>>6, bq=rem%16, l=rem/16, b=bq*4+j;
        v = P202[(c*8+l)*64 + b];
    }
    W[idx] = v;
}

// ---------------- CSR construction (verified) ----------------
__global__ __launch_bounds__(256) void count_kernel(const int* __restrict__ dst,
                                                    int* __restrict__ cnt)
{
    int e = blockIdx.x*256 + threadIdx.x;
    if (e < EDGES) atomicAdd(&cnt[dst[e]], 1);
}

__global__ __launch_bounds__(256) void scan_kernel(const int* __restrict__ cnt,
                                                   int* __restrict__ off,
                                                   int* __restrict__ cursor)
{
    __shared__ int s_part[256];
    const int t = threadIdx.x;
    const int base = t * 64;
    int sum = 0;
    for (int i = 0; i < 64; ++i) sum += cnt[base + i];
    s_part[t] = sum;
    __syncthreads();
    for (int d = 1; d < 256; d <<= 1) {
        int add = (t >= d) ? s_part[t - d] : 0;
        __syncthreads();
        s_part[t] += add;
        __syncthreads();
    }
    int run = s_part[t] - sum;
    for (int i = 0; i < 64; ++i) {
        int c = cnt[base + i];
        off[base + i]    = run;
        cursor[base + i] = run;
        run += c;
    }
    if (t == 255) off[NODES] = run;
}

__global__ __launch_bounds__(256) void scatter_kernel(const int* __restrict__ dst,
                                                      int* __restrict__ cursor,
                                                      int* __restrict__ eidx)
{
    int e = blockIdx.x*256 + threadIdx.x;
    if (e < EDGES) {
        int pos = atomicAdd(&cursor[dst[e]], 1);
        eidx[pos] = e;
    }
}

// ---------------- main edge kernel: array-free, packed-P ----------------
__global__ __launch_bounds__(NTHREADS, 2) void edge_kernel(
    const float* __restrict__ xa_g, const float* __restrict__ xv_g, const float* __restrict__ xd_g,
    const float* __restrict__ rij_g,
    const float* __restrict__ PA,  const float* __restrict__ PVv, const float* __restrict__ PVs,
    const float* __restrict__ PDd, const float* __restrict__ PDv, const float* __restrict__ PDs,
    const int* __restrict__ src, const int* __restrict__ dst, const int* __restrict__ eidx,
    float* __restrict__ out)
{
    __shared__ __align__(16) float s_FS [EB][112];   // xa[0,64) sv[64,96) sd[96,112)
    __shared__ __align__(16) float s_FVT[EB][288];   // [i<3][b<96]: xv[0,32) uv[32,48) cr[48,80) wd[80,96)
    __shared__ __align__(16) float s_FDT[EB][144];   // [k<9][b<16]: xd
    __shared__ float s_m[EB][OUT_CH];
    __shared__ float s_rad[EB][8];
    __shared__ float s_rh[EB][4];
    __shared__ int   s_dst[EB];
    __shared__ int   s_srcn[EB];

    const int t  = threadIdx.x;
    const int e0 = blockIdx.x * EB;

    // ---- phase 1a: per-edge radial basis + rh (16 lanes) ----
    if (t < EB) {
        const int e = eidx[e0 + t];            // CSR order: s_dst non-decreasing
        float r0 = rij_g[e*3+0];
        float r1 = rij_g[e*3+1];
        float r2 = rij_g[e*3+2];
        float x_sq = (r0*r0 + r1*r1 + r2*r2) * 0.125f;
        float q  = sqrtf(x_sq);
        float w  = fmaxf(1.0f - x_sq, 0.0f);
        const float PI = 3.14159265358979323846f;
        for (int n = 0; n < 8; ++n)
            s_rad[t][n] = cosf(PI * (float)n * q) * w;
        float y0 = r0*0.875f, y1 = r1*0.875f, y2 = r2*0.875f;
        float nn = sqrtf(y0*y0 + y1*y1 + y2*y2);
        float sc = tanhf(nn) / fmaxf(nn, 1e-6f);
        s_rh[t][0] = y0*sc; s_rh[t][1] = y1*sc; s_rh[t][2] = y2*sc; s_rh[t][3] = 0.f;
        s_dst[t]  = dst[e];
        s_srcn[t] = src[e];
    }
    __syncthreads();

    // ---- phase 1b: gather node features into packed LDS layouts ----
    {
        const int el  = t >> 4;
        const int sub = t & 15;
        const int n   = s_srcn[el];
        const float rh0 = s_rh[el][0], rh1 = s_rh[el][1], rh2 = s_rh[el][2];
        #pragma unroll
        for (int k = 0; k < 4; ++k) {
            int b = sub + 16*k;
            s_FS[el][b] = xa_g[n*64 + b];
        }
        #pragma unroll
        for (int k = 0; k < 2; ++k) {
            int b = sub + 16*k;
            float v0 = xv_g[(n*32 + b)*3 + 0];
            float v1 = xv_g[(n*32 + b)*3 + 1];
            float v2 = xv_g[(n*32 + b)*3 + 2];
            s_FVT[el][0*96 + b] = v0;
            s_FVT[el][1*96 + b] = v1;
            s_FVT[el][2*96 + b] = v2;
            s_FS[el][64 + b] = rh0*v0 + rh1*v1 + rh2*v2;          // sv
            s_FVT[el][0*96 + 48 + b] = rh1*v2 - rh2*v1;           // cr
            s_FVT[el][1*96 + 48 + b] = rh2*v0 - rh0*v2;
            s_FVT[el][2*96 + 48 + b] = rh0*v1 - rh1*v0;
        }
        {
            const int b = sub;
            const float d0 = xd_g[(n*16+b)*9+0], d1 = xd_g[(n*16+b)*9+1], d2 = xd_g[(n*16+b)*9+2];
            const float d3 = xd_g[(n*16+b)*9+3], d4 = xd_g[(n*16+b)*9+4], d5 = xd_g[(n*16+b)*9+5];
            const float d6 = xd_g[(n*16+b)*9+6], d7 = xd_g[(n*16+b)*9+7], d8 = xd_g[(n*16+b)*9+8];
            s_FDT[el][0*16+b]=d0; s_FDT[el][1*16+b]=d1; s_FDT[el][2*16+b]=d2;
            s_FDT[el][3*16+b]=d3; s_FDT[el][4*16+b]=d4; s_FDT[el][5*16+b]=d5;
            s_FDT[el][6*16+b]=d6; s_FDT[el][7*16+b]=d7; s_FDT[el][8*16+b]=d8;
            const float uv0 = d0*rh0 + d1*rh1 + d2*rh2;
            const float uv1 = d3*rh0 + d4*rh1 + d5*rh2;
            const float uv2 = d6*rh0 + d7*rh1 + d8*rh2;
            s_FVT[el][0*96 + 32 + b] = uv0;
            s_FVT[el][1*96 + 32 + b] = uv1;
            s_FVT[el][2*96 + 32 + b] = uv2;
            s_FVT[el][0*96 + 80 + b] = rh0*d0 + rh1*d3 + rh2*d6;  // wd
            s_FVT[el][1*96 + 80 + b] = rh0*d1 + rh1*d4 + rh2*d7;
            s_FVT[el][2*96 + 80 + b] = rh0*d2 + rh1*d5 + rh2*d8;
            s_FS[el][96 + b] = rh0*uv0 + rh1*uv1 + rh2*uv2;       // sd
        }
    }
    __syncthreads();

    // ---- pass A: m_a, c in [0,64), 4 edges/thread ----
    {
        const int c = t & 63, eg = t >> 6, el0 = eg*4;
        RADROW(pa, el0); RADROW(pb, el0+1); RADROW(pc, el0+2); RADROW(pd, el0+3);
        float a0=0.f, a1=0.f, a2=0.f, a3=0.f;
        const float4* __restrict__ P4 = ((const float4*)PA) + c;
        for (int bq = 0; bq < 28; ++bq) {
            LOADQ8(P4, 28, 64);
            { TCOMP(t0,pa); const float4 f=((const float4*)&s_FS[el0  ][0])[bq]; DOT4(a0,t0,f); }
            { TCOMP(t1,pb); const float4 f=((const float4*)&s_FS[el0+1][0])[bq]; DOT4(a1,t1,f); }
            { TCOMP(t2,pc); const float4 f=((const float4*)&s_FS[el0+2][0])[bq]; DOT4(a2,t2,f); }
            { TCOMP(t3,pd); const float4 f=((const float4*)&s_FS[el0+3][0])[bq]; DOT4(a3,t3,f); }
        }
        s_m[el0  ][c] = a0;
        s_m[el0+1][c] = a1;
        s_m[el0+2][c] = a2;
        s_m[el0+3][c] = a3;
    }

    // ---- pass V: m_v, c in [0,32), 2 edges/thread ----
    {
        const int c = t & 31, eg = t >> 5, el0 = eg*2, el1 = el0+1;
        RADROW(pa, el0); RADROW(pb, el1);
        float av0=0.f,av1=0.f,av2=0.f, bv0=0.f,bv1=0.f,bv2=0.f, as0=0.f, bs0=0.f;
        const float4* __restrict__ Pv4 = ((const float4*)PVv) + c;
        for (int bq = 0; bq < 24; ++bq) {
            LOADQ8(Pv4, 24, 32);
            { TCOMP(t0,pa);
              const float4 g0=((const float4*)&s_FVT[el0][0])[bq];
              const float4 g1=((const float4*)&s_FVT[el0][0])[24+bq];
              const float4 g2=((const float4*)&s_FVT[el0][0])[48+bq];
              DOT4(av0,t0,g0); DOT4(av1,t0,g1); DOT4(av2,t0,g2); }
            { TCOMP(t1,pb);
              const float4 g0=((const float4*)&s_FVT[el1][0])[bq];
              const float4 g1=((const float4*)&s_FVT[el1][0])[24+bq];
              const float4 g2=((const float4*)&s_FVT[el1][0])[48+bq];
              DOT4(bv0,t1,g0); DOT4(bv1,t1,g1); DOT4(bv2,t1,g2); }
        }
        const float4* __restrict__ Ps4 = ((const float4*)PVs) + c;
        for (int bq = 0; bq < 24; ++bq) {
            LOADQ8(Ps4, 24, 32);
            { TCOMP(t0,pa); const float4 f=((const float4*)&s_FS[el0][0])[bq]; DOT4(as0,t0,f); }
            { TCOMP(t1,pb); const float4 f=((const float4*)&s_FS[el1][0])[bq]; DOT4(bs0,t1,f); }
        }
        s_m[el0][64 + c*3 + 0] = av0 + s_rh[el0][0]*as0;
        s_m[el0][64 + c*3 + 1] = av1 + s_rh[el0][1]*as0;
        s_m[el0][64 + c*3 + 2] = av2 + s_rh[el0][2]*as0;
        s_m[el1][64 + c*3 + 0] = bv0 + s_rh[el1][0]*bs0;
        s_m[el1][64 + c*3 + 1] = bv1 + s_rh[el1][1]*bs0;
        s_m[el1][64 + c*3 + 2] = bv2 + s_rh[el1][2]*bs0;
    }

    // ---- pass D: m_d, c in [0,16), 1 edge/thread ----
    {
        const int c = t & 15, el = t >> 4;
        RADROW(pa, el);
        float ad0=0.f,ad1=0.f,ad2=0.f,ad3=0.f,ad4=0.f,ad5=0.f,ad6=0.f,ad7=0.f,ad8=0.f;
        float aj0=0.f,aj1=0.f,aj2=0.f, a00=0.f;
        const float4* __restrict__ Pd4 = ((const float4*)PDd) + c;
        for (int bq = 0; bq < 4; ++bq) {
            LOADQ8(Pd4, 4, 16);
            TCOMP(t0,pa);
            { const float4 h=((const float4*)&s_FDT[el][0])[0*4+bq]; DOT4(ad0,t0,h); }
            { const float4 h=((const float4*)&s_FDT[el][0])[1*4+bq]; DOT4(ad1,t0,h); }
            { const float4 h=((const float4*)&s_FDT[el][0])[2*4+bq]; DOT4(ad2,t0,h); }
            { const float4 h=((const float4*)&s_FDT[el][0])[3*4+bq]; DOT4(ad3,t0,h); }
            { const float4 h=((const float4*)&s_FDT[el][0])[4*4+bq]; DOT4(ad4,t0,h); }
            { const float4 h=((const float4*)&s_FDT[el][0])[5*4+bq]; DOT4(ad5,t0,h); }
            { const float4 h=((const float4*)&s_FDT[el][0])[6*4+bq]; DOT4(ad6,t0,h); }
            { const float4 h=((const float4*)&s_FDT[el][0])[7*4+bq]; DOT4(ad7,t0,h); }
            { const float4 h=((const float4*)&s_FDT[el][0])[8*4+bq]; DOT4(ad8,t0,h); }
        }
        const float4* __restrict__ Pw4 = ((const float4*)PDv) + c;
        for (int bq = 0; bq < 24; ++bq) {
            LOADQ8(Pw4, 24, 16);
            TCOMP(t0,pa);
            const float4 g0=((const float4*)&s_FVT[el][0])[bq];
            const float4 g1=((const float4*)&s_FVT[el][0])[24+bq];
            const float4 g2=((const float4*)&s_FVT[el][0])[48+bq];
            DOT4(aj0,t0,g0); DOT4(aj1,t0,g1); DOT4(aj2,t0,g2);
        }
        const float4* __restrict__ Px4 = ((const float4*)PDs) + c;
        for (int bq = 0; bq < 16; ++bq) {
            LOADQ8(Px4, 16, 16);
            TCOMP(t0,pa);
            const float4 f=((const float4*)&s_FS[el][0])[bq]; DOT4(a00,t0,f);
        }
        const float rr0 = s_rh[el][0], rr1 = s_rh[el][1], rr2 = s_rh[el][2];
        s_m[el][160 + c*9 + 0] = ad0 + rr0*(aj0 + rr0*a00);
        s_m[el][160 + c*9 + 1] = ad1 + rr0*(aj1 + rr1*a00);
        s_m[el][160 + c*9 + 2] = ad2 + rr0*(aj2 + rr2*a00);
        s_m[el][160 + c*9 + 3] = ad3 + rr1*(aj0 + rr0*a00);
        s_m[el][160 + c*9 + 4] = ad4 + rr1*(aj1 + rr1*a00);
        s_m[el][160 + c*9 + 5] = ad5 + rr1*(aj2 + rr2*a00);
        s_m[el][160 + c*9 + 6] = ad6 + rr2*(aj0 + rr0*a00);
        s_m[el][160 + c*9 + 7] = ad7 + rr2*(aj1 + rr1*a00);
        s_m[el][160 + c*9 + 8] = ad8 + rr2*(aj2 + rr2*a00);
    }
    __syncthreads();

    // ---- segmented emit: s_dst non-decreasing -> one atomic per (segment, channel) ----
    for (int ch = t; ch < OUT_CH; ch += NTHREADS) {
        float run = 0.0f;
        #pragma unroll
        for (int el = 0; el < EB; ++el) {
            run += s_m[el][ch];
            if (el == EB-1 || s_dst[el+1] != s_dst[el]) {
                atomicAdd(&out[(size_t)s_dst[el]*OUT_CH + ch], run);
                run = 0.0f;
            }
        }
    }
}

extern "C" void kernel_launch(void* const* d_in, const int* in_sizes, int n_in,
                              void* d_out, int out_size, void* d_ws, size_t ws_size,
                              hipStream_t stream)
{
    const float* xa  = (const float*)d_in[0];
    const float* xv  = (const float*)d_in[1];
    const float* xd  = (const float*)d_in[2];
    const float* rij = (const float*)d_in[3];
    const float* P000 = (const float*)d_in[4];
    const float* P110 = (const float*)d_in[5];
    const float* P220 = (const float*)d_in[6];
    const float* P011 = (const float*)d_in[7];
    const float* P101 = (const float*)d_in[8];
    const float* P121 = (const float*)d_in[9];
    const float* P211 = (const float*)d_in[10];
    const float* P111 = (const float*)d_in[11];
    const float* P022 = (const float*)d_in[12];
    const float* P112 = (const float*)d_in[13];
    const float* P202 = (const float*)d_in[14];
    const float* P222 = (const float*)d_in[15];
    const float* P212 = (const float*)d_in[16];
    const int* src = (const int*)d_in[17];
    const int* dst = (const int*)d_in[18];

    float* W = (float*)d_ws;
    int* ip     = (int*)d_ws + PACK_TOTAL;
    int* cnt    = ip;
    int* off    = ip + NODES;
    int* cursor = off + NODES + 1;
    int* eidx   = cursor + NODES;

    hipMemsetAsync(cnt, 0, NODES * sizeof(int), stream);
    hipMemsetAsync(d_out, 0, (size_t)out_size * sizeof(float), stream);

    pack_kernel<<<(PACK_TOTAL + 255)/256, 256, 0, stream>>>(
        P000, P110, P220, P011, P101, P121, P211, P111,
        P022, P112, P202, P222, P212, W);
    count_kernel  <<<EDGES/256, 256, 0, stream>>>(dst, cnt);
    scan_kernel   <<<1,         256, 0, stream>>>(cnt, off, cursor);
    scatter_kernel<<<EDGES/256, 256, 0, stream>>>(dst, cursor, eidx);

    edge_kernel<<<EDGES/EB, NTHREADS, 0, stream>>>(
        xa, xv, xd, rij,
        W + OFF_PA, W + OFF_PVV, W + OFF_PVS, W + OFF_PDD, W + OFF_PDV, W + OFF_PDS,
        src, dst, eidx, (float*)d_out);
}

// Round 7
// 631.875 us; speedup vs baseline: 53.0148x; 3.7135x over previous
//
#include <hip/hip_runtime.h>

#define NODES    16384
#define EDGES    262144
#define OUT_CH   304      // 64 + 32*3 + 16*9
#define EB       16       // edges per block
#define NTHREADS 256

typedef __attribute__((ext_vector_type(8))) short short8;
typedef __attribute__((ext_vector_type(4))) float f32x4;
#define MFMA(a,b,c) __builtin_amdgcn_mfma_f32_16x16x32_bf16((a),(b),(c),0,0,0)

// ---------- packed-B (bf16) sizes ----------
// B1: K=896 (BW=112), 7 N-tiles  -> 28*7*64*8 = 100352 ushort
// B2: K=768 (BW=96),  3 N-tiles  -> 24*3*64*8 =  36864 ushort
// B3: K=128 (BW=16),  1 N-tile   ->  4*1*64*8 =   2048 ushort
#define NB1 100352
#define NB2 36864
#define NB3 2048
#define NPACK (NB1 + NB2 + NB3)     // 139264 ushort = 278528 B (4B-aligned)

__device__ __forceinline__ short f2bf(float f) {
    union { float f; unsigned int i; } x; x.f = f;
    unsigned int i = x.i;
    i += 0x7fffu + ((i >> 16) & 1u);
    return (short)(i >> 16);
}

// ---------------- B prepack: exact B-fragment order, bf16 ----------------
__global__ __launch_bounds__(256) void packb_kernel(
    const float* __restrict__ P000, const float* __restrict__ P110, const float* __restrict__ P220,
    const float* __restrict__ P011, const float* __restrict__ P101, const float* __restrict__ P121,
    const float* __restrict__ P211, const float* __restrict__ P111,
    const float* __restrict__ P022, const float* __restrict__ P112, const float* __restrict__ P202,
    const float* __restrict__ P222, const float* __restrict__ P212,
    unsigned short* __restrict__ BP)
{
    int idx = blockIdx.x*256 + threadIdx.x;
    if (idx >= NPACK) return;
    float v = 0.0f;
    if (idx < NB1) {                       // GEMM1: BW=112
        int j = idx & 7, lane = (idx >> 3) & 63, q = idx >> 9;
        int tile = q % 7, kk = q / 7;
        int n = tile*16 + (lane & 15);
        int k = kk*32 + (lane >> 4)*8 + j;
        int l = k / 112, b = k % 112;
        if (n < 64) {           int c = n;
            if      (b <  64) v = P000[(c*8+l)*64 + b];
            else if (b <  96) v = P110[(c*8+l)*32 + (b-64)];
            else              v = P220[(c*8+l)*16 + (b-96)];
        } else if (n < 96) {    int c = n - 64;      // as0
            if      (b <  64) v = P101[(c*8+l)*64 + b];
            else if (b <  96) v = P211[(c*8+l)*32 + (b-64)];
        } else {                int c = n - 96;      // a00
            if      (b <  64) v = P202[(c*8+l)*64 + b];
        }
    } else if (idx < NB1 + NB2) {          // GEMM2: BW=96
        int o = idx - NB1;
        int j = o & 7, lane = (o >> 3) & 63, q = o >> 9;
        int tile = q % 3, kk = q / 3;
        int n = tile*16 + (lane & 15);
        int k = kk*32 + (lane >> 4)*8 + j;
        int l = k / 96, b = k % 96;
        if (n < 32) {           int c = n;           // av
            if      (b <  32) v = P011[(c*8+l)*32 + b];
            else if (b <  48) v = P121[(c*8+l)*16 + (b-32)];
            else if (b <  80) v = P111[(c*8+l)*32 + (b-48)];
        } else {                int c = n - 32;      // aj
            if      (b <  32) v = P112[(c*8+l)*32 + b];
            else if (b <  48) v = 0.0f;
            else if (b <  80) v = P212[(c*8+l)*32 + (b-48)];
            else              v = P222[(c*8+l)*16 + (b-80)];
        }
    } else {                               // GEMM3: BW=16
        int o = idx - NB1 - NB2;
        int j = o & 7, lane = (o >> 3) & 63, kk = o >> 9;
        int n = lane & 15;
        int k = kk*32 + (lane >> 4)*8 + j;
        int l = k / 16, b = k % 16;
        v = P022[(n*8+l)*16 + b];
    }
    union { float f; unsigned int i; } x; x.f = v;
    unsigned int i = x.i;
    i += 0x7fffu + ((i >> 16) & 1u);
    BP[idx] = (unsigned short)(i >> 16);
}

// ---------------- CSR construction (verified) ----------------
__global__ __launch_bounds__(256) void count_kernel(const int* __restrict__ dst,
                                                    int* __restrict__ cnt)
{
    int e = blockIdx.x*256 + threadIdx.x;
    if (e < EDGES) atomicAdd(&cnt[dst[e]], 1);
}

__global__ __launch_bounds__(256) void scan_kernel(const int* __restrict__ cnt,
                                                   int* __restrict__ off,
                                                   int* __restrict__ cursor)
{
    __shared__ int s_part[256];
    const int t = threadIdx.x;
    const int base = t * 64;
    int sum = 0;
    for (int i = 0; i < 64; ++i) sum += cnt[base + i];
    s_part[t] = sum;
    __syncthreads();
    for (int d = 1; d < 256; d <<= 1) {
        int add = (t >= d) ? s_part[t - d] : 0;
        __syncthreads();
        s_part[t] += add;
        __syncthreads();
    }
    int run = s_part[t] - sum;
    for (int i = 0; i < 64; ++i) {
        int c = cnt[base + i];
        off[base + i]    = run;
        cursor[base + i] = run;
        run += c;
    }
    if (t == 255) off[NODES] = run;
}

__global__ __launch_bounds__(256) void scatter_kernel(const int* __restrict__ dst,
                                                      int* __restrict__ cursor,
                                                      int* __restrict__ eidx)
{
    int e = blockIdx.x*256 + threadIdx.x;
    if (e < EDGES) {
        int pos = atomicAdd(&cursor[dst[e]], 1);
        eidx[pos] = e;
    }
}

// A-fragment on the fly: lane holds z[m][k..k+7], k = kk*32 + quad*8, z = rad[l]*feat[b]
template<int BW>
__device__ __forceinline__ short8 build_afrag(const float* __restrict__ frow,
                                              const float* __restrict__ radrow,
                                              int kbase)
{
    const int l  = kbase / BW;
    const int b0 = kbase % BW;            // multiple of 8 (BW % 8 == 0)
    const float r = radrow[l];
    const float4 f0 = *reinterpret_cast<const float4*>(frow + b0);
    const float4 f1 = *reinterpret_cast<const float4*>(frow + b0 + 4);
    short8 a;
    a[0] = f2bf(r*f0.x); a[1] = f2bf(r*f0.y); a[2] = f2bf(r*f0.z); a[3] = f2bf(r*f0.w);
    a[4] = f2bf(r*f1.x); a[5] = f2bf(r*f1.y); a[6] = f2bf(r*f1.z); a[7] = f2bf(r*f1.w);
    return a;
}

// ---------------- main edge kernel: MFMA ----------------
__global__ __launch_bounds__(NTHREADS, 2) void edge_kernel(
    const float* __restrict__ xa_g, const float* __restrict__ xv_g, const float* __restrict__ xd_g,
    const float* __restrict__ rij_g,
    const unsigned short* __restrict__ BP,
    const int* __restrict__ src, const int* __restrict__ dst, const int* __restrict__ eidx,
    float* __restrict__ out)
{
    __shared__ __align__(16) float s_FS [EB][112];   // xa[0,64) sv[64,96) sd[96,112)
    __shared__ __align__(16) float s_FVT[EB][288];   // [i<3][b<96]: xv[0,32) uv[32,48) cr[48,80) wd[80,96)
    __shared__ __align__(16) float s_FDT[EB][144];   // [k<9][b<16]
    __shared__ float s_m[EB][OUT_CH];
    __shared__ float s_as0[EB][32];
    __shared__ float s_a00[EB][16];
    __shared__ float s_aj[EB][3][16];
    __shared__ float s_rad[EB][8];
    __shared__ float s_rh[EB][4];
    __shared__ int   s_dst[EB];
    __shared__ int   s_srcn[EB];

    const int t  = threadIdx.x;
    const int e0 = blockIdx.x * EB;
    const int lane = t & 63, wid = t >> 6;
    const int col = lane & 15, quad = lane >> 4;

    const short8* __restrict__ B1 = (const short8*)BP;
    const short8* __restrict__ B2 = (const short8*)(BP + NB1);
    const short8* __restrict__ B3 = (const short8*)(BP + NB1 + NB2);

    // ---- phase 1a: per-edge radial basis + rh ----
    if (t < EB) {
        const int e = eidx[e0 + t];            // CSR order: s_dst non-decreasing
        float r0 = rij_g[e*3+0];
        float r1 = rij_g[e*3+1];
        float r2 = rij_g[e*3+2];
        float x_sq = (r0*r0 + r1*r1 + r2*r2) * 0.125f;
        float q  = sqrtf(x_sq);
        float w  = fmaxf(1.0f - x_sq, 0.0f);
        const float PI = 3.14159265358979323846f;
        for (int n = 0; n < 8; ++n)
            s_rad[t][n] = cosf(PI * (float)n * q) * w;
        float y0 = r0*0.875f, y1 = r1*0.875f, y2 = r2*0.875f;
        float nn = sqrtf(y0*y0 + y1*y1 + y2*y2);
        float sc = tanhf(nn) / fmaxf(nn, 1e-6f);
        s_rh[t][0] = y0*sc; s_rh[t][1] = y1*sc; s_rh[t][2] = y2*sc; s_rh[t][3] = 0.f;
        s_dst[t]  = dst[e];
        s_srcn[t] = src[e];
    }
    __syncthreads();

    // ---- phase 1b: gather node features into LDS (verified layout) ----
    {
        const int el  = t >> 4;
        const int sub = t & 15;
        const int n   = s_srcn[el];
        const float rh0 = s_rh[el][0], rh1 = s_rh[el][1], rh2 = s_rh[el][2];
        #pragma unroll
        for (int k = 0; k < 4; ++k) {
            int b = sub + 16*k;
            s_FS[el][b] = xa_g[n*64 + b];
        }
        #pragma unroll
        for (int k = 0; k < 2; ++k) {
            int b = sub + 16*k;
            float v0 = xv_g[(n*32 + b)*3 + 0];
            float v1 = xv_g[(n*32 + b)*3 + 1];
            float v2 = xv_g[(n*32 + b)*3 + 2];
            s_FVT[el][0*96 + b] = v0;
            s_FVT[el][1*96 + b] = v1;
            s_FVT[el][2*96 + b] = v2;
            s_FS[el][64 + b] = rh0*v0 + rh1*v1 + rh2*v2;          // sv
            s_FVT[el][0*96 + 48 + b] = rh1*v2 - rh2*v1;           // cr
            s_FVT[el][1*96 + 48 + b] = rh2*v0 - rh0*v2;
            s_FVT[el][2*96 + 48 + b] = rh0*v1 - rh1*v0;
        }
        {
            const int b = sub;
            const float d0 = xd_g[(n*16+b)*9+0], d1 = xd_g[(n*16+b)*9+1], d2 = xd_g[(n*16+b)*9+2];
            const float d3 = xd_g[(n*16+b)*9+3], d4 = xd_g[(n*16+b)*9+4], d5 = xd_g[(n*16+b)*9+5];
            const float d6 = xd_g[(n*16+b)*9+6], d7 = xd_g[(n*16+b)*9+7], d8 = xd_g[(n*16+b)*9+8];
            s_FDT[el][0*16+b]=d0; s_FDT[el][1*16+b]=d1; s_FDT[el][2*16+b]=d2;
            s_FDT[el][3*16+b]=d3; s_FDT[el][4*16+b]=d4; s_FDT[el][5*16+b]=d5;
            s_FDT[el][6*16+b]=d6; s_FDT[el][7*16+b]=d7; s_FDT[el][8*16+b]=d8;
            const float uv0 = d0*rh0 + d1*rh1 + d2*rh2;
            const float uv1 = d3*rh0 + d4*rh1 + d5*rh2;
            const float uv2 = d6*rh0 + d7*rh1 + d8*rh2;
            s_FVT[el][0*96 + 32 + b] = uv0;
            s_FVT[el][1*96 + 32 + b] = uv1;
            s_FVT[el][2*96 + 32 + b] = uv2;
            s_FVT[el][0*96 + 80 + b] = rh0*d0 + rh1*d3 + rh2*d6;  // wd
            s_FVT[el][1*96 + 80 + b] = rh0*d1 + rh1*d4 + rh2*d7;
            s_FVT[el][2*96 + 80 + b] = rh0*d2 + rh1*d5 + rh2*d8;
            s_FS[el][96 + b] = rh0*uv0 + rh1*uv1 + rh2*uv2;       // sd
        }
    }
    __syncthreads();

    // ---- GEMM phase: wave-split MFMA.  D row = quad*4+reg (edge), col = lane&15 (chan) ----
    const float* __restrict__ radrow = &s_rad[col][0];
    const int r0 = quad*4;

    if (wid == 0) {
        // z_A x {m_a cols 0..63}
        const float* frow = &s_FS[col][0];
        f32x4 c0 = {0,0,0,0}, c1 = {0,0,0,0}, c2 = {0,0,0,0}, c3 = {0,0,0,0};
        for (int kk = 0; kk < 28; ++kk) {
            short8 a = build_afrag<112>(frow, radrow, kk*32 + quad*8);
            const short8* bp = B1 + (kk*7)*64 + lane;
            c0 = MFMA(a, bp[0*64], c0);
            c1 = MFMA(a, bp[1*64], c1);
            c2 = MFMA(a, bp[2*64], c2);
            c3 = MFMA(a, bp[3*64], c3);
        }
        #pragma unroll
        for (int r = 0; r < 4; ++r) {
            s_m[r0+r][ 0+col] = c0[r];
            s_m[r0+r][16+col] = c1[r];
            s_m[r0+r][32+col] = c2[r];
            s_m[r0+r][48+col] = c3[r];
        }
    } else if (wid == 1) {
        // z_A x {as0 (tiles 4,5), a00 (tile 6)}; then z_D^ij x P022
        const float* frow = &s_FS[col][0];
        f32x4 c4 = {0,0,0,0}, c5 = {0,0,0,0}, c6 = {0,0,0,0};
        for (int kk = 0; kk < 28; ++kk) {
            short8 a = build_afrag<112>(frow, radrow, kk*32 + quad*8);
            const short8* bp = B1 + (kk*7)*64 + lane;
            c4 = MFMA(a, bp[4*64], c4);
            c5 = MFMA(a, bp[5*64], c5);
            c6 = MFMA(a, bp[6*64], c6);
        }
        #pragma unroll
        for (int r = 0; r < 4; ++r) {
            s_as0[r0+r][ 0+col] = c4[r];
            s_as0[r0+r][16+col] = c5[r];
            s_a00[r0+r][col]    = c6[r];
        }
        for (int ij = 0; ij < 9; ++ij) {
            const float* fd = &s_FDT[col][ij*16];
            f32x4 d = {0,0,0,0};
            #pragma unroll
            for (int kk = 0; kk < 4; ++kk) {
                short8 a = build_afrag<16>(fd, radrow, kk*32 + quad*8);
                d = MFMA(a, B3[kk*64 + lane], d);
            }
            #pragma unroll
            for (int r = 0; r < 4; ++r)
                s_m[r0+r][160 + col*9 + ij] = d[r];
        }
    } else if (wid == 2) {
        // z_V^0 x {av0 t0,t1; aj0 t2}; z_V^1 x {av1 t0,t1}
        const float* f0 = &s_FVT[col][0*96];
        const float* f1 = &s_FVT[col][1*96];
        f32x4 c00={0,0,0,0}, c01={0,0,0,0}, c02={0,0,0,0}, c10={0,0,0,0}, c11={0,0,0,0};
        for (int kk = 0; kk < 24; ++kk) {
            short8 a0 = build_afrag<96>(f0, radrow, kk*32 + quad*8);
            short8 a1 = build_afrag<96>(f1, radrow, kk*32 + quad*8);
            const short8* bp = B2 + (kk*3)*64 + lane;
            short8 b0 = bp[0*64], b1 = bp[1*64], b2 = bp[2*64];
            c00 = MFMA(a0, b0, c00);
            c01 = MFMA(a0, b1, c01);
            c02 = MFMA(a0, b2, c02);
            c10 = MFMA(a1, b0, c10);
            c11 = MFMA(a1, b1, c11);
        }
        #pragma unroll
        for (int r = 0; r < 4; ++r) {
            s_m[r0+r][64 + ( 0+col)*3 + 0] = c00[r];
            s_m[r0+r][64 + (16+col)*3 + 0] = c01[r];
            s_aj[r0+r][0][col]             = c02[r];
            s_m[r0+r][64 + ( 0+col)*3 + 1] = c10[r];
            s_m[r0+r][64 + (16+col)*3 + 1] = c11[r];
        }
    } else {
        // z_V^1 x {aj1 t2}; z_V^2 x {av2 t0,t1; aj2 t2}
        const float* f1 = &s_FVT[col][1*96];
        const float* f2 = &s_FVT[col][2*96];
        f32x4 c12={0,0,0,0}, c20={0,0,0,0}, c21={0,0,0,0}, c22={0,0,0,0};
        for (int kk = 0; kk < 24; ++kk) {
            short8 a1 = build_afrag<96>(f1, radrow, kk*32 + quad*8);
            short8 a2 = build_afrag<96>(f2, radrow, kk*32 + quad*8);
            const short8* bp = B2 + (kk*3)*64 + lane;
            short8 b0 = bp[0*64], b1 = bp[1*64], b2 = bp[2*64];
            c12 = MFMA(a1, b2, c12);
            c20 = MFMA(a2, b0, c20);
            c21 = MFMA(a2, b1, c21);
            c22 = MFMA(a2, b2, c22);
        }
        #pragma unroll
        for (int r = 0; r < 4; ++r) {
            s_aj[r0+r][1][col]             = c12[r];
            s_m[r0+r][64 + ( 0+col)*3 + 2] = c20[r];
            s_m[r0+r][64 + (16+col)*3 + 2] = c21[r];
            s_aj[r0+r][2][col]             = c22[r];
        }
    }
    __syncthreads();

    // ---- combine: recouple rh factors ----
    // m_v[el][c][i] += rh[i] * as0[el][c]
    #pragma unroll
    for (int it = t; it < EB*32; it += NTHREADS) {
        const int el = it >> 5, c = it & 31;
        const float as0 = s_as0[el][c];
        s_m[el][64 + c*3 + 0] += s_rh[el][0]*as0;
        s_m[el][64 + c*3 + 1] += s_rh[el][1]*as0;
        s_m[el][64 + c*3 + 2] += s_rh[el][2]*as0;
    }
    // m_d[el][c][i][j] += rh[i]*(aj[j] + rh[j]*a00)
    {
        const int el = t >> 4, c = t & 15;
        const float a00 = s_a00[el][c];
        const float aj0 = s_aj[el][0][c], aj1 = s_aj[el][1][c], aj2 = s_aj[el][2][c];
        const float rr0 = s_rh[el][0], rr1 = s_rh[el][1], rr2 = s_rh[el][2];
        const float g0 = aj0 + rr0*a00, g1 = aj1 + rr1*a00, g2 = aj2 + rr2*a00;
        float* md = &s_m[el][160 + c*9];
        md[0] += rr0*g0; md[1] += rr0*g1; md[2] += rr0*g2;
        md[3] += rr1*g0; md[4] += rr1*g1; md[5] += rr1*g2;
        md[6] += rr2*g0; md[7] += rr2*g1; md[8] += rr2*g2;
    }
    __syncthreads();

    // ---- segmented emit: s_dst non-decreasing -> one atomic per (segment, channel) ----
    for (int ch = t; ch < OUT_CH; ch += NTHREADS) {
        float run = 0.0f;
        #pragma unroll
        for (int el = 0; el < EB; ++el) {
            run += s_m[el][ch];
            if (el == EB-1 || s_dst[el+1] != s_dst[el]) {
                atomicAdd(&out[(size_t)s_dst[el]*OUT_CH + ch], run);
                run = 0.0f;
            }
        }
    }
}

extern "C" void kernel_launch(void* const* d_in, const int* in_sizes, int n_in,
                              void* d_out, int out_size, void* d_ws, size_t ws_size,
                              hipStream_t stream)
{
    const float* xa  = (const float*)d_in[0];
    const float* xv  = (const float*)d_in[1];
    const float* xd  = (const float*)d_in[2];
    const float* rij = (const float*)d_in[3];
    const float* P000 = (const float*)d_in[4];
    const float* P110 = (const float*)d_in[5];
    const float* P220 = (const float*)d_in[6];
    const float* P011 = (const float*)d_in[7];
    const float* P101 = (const float*)d_in[8];
    const float* P121 = (const float*)d_in[9];
    const float* P211 = (const float*)d_in[10];
    const float* P111 = (const float*)d_in[11];
    const float* P022 = (const float*)d_in[12];
    const float* P112 = (const float*)d_in[13];
    const float* P202 = (const float*)d_in[14];
    const float* P222 = (const float*)d_in[15];
    const float* P212 = (const float*)d_in[16];
    const int* src = (const int*)d_in[17];
    const int* dst = (const int*)d_in[18];

    unsigned short* BP = (unsigned short*)d_ws;
    int* ip     = (int*)d_ws + (NPACK/2);   // NPACK ushort = NPACK/2 ints
    int* cnt    = ip;
    int* off    = ip + NODES;
    int* cursor = off + NODES + 1;
    int* eidx   = cursor + NODES;

    hipMemsetAsync(cnt, 0, NODES * sizeof(int), stream);
    hipMemsetAsync(d_out, 0, (size_t)out_size * sizeof(float), stream);

    packb_kernel<<<(NPACK + 255)/256, 256, 0, stream>>>(
        P000, P110, P220, P011, P101, P121, P211, P111,
        P022, P112, P202, P222, P212, BP);
    count_kernel  <<<EDGES/256, 256, 0, stream>>>(dst, cnt);
    scan_kernel   <<<1,         256, 0, stream>>>(cnt, off, cursor);
    scatter_kernel<<<EDGES/256, 256, 0, stream>>>(dst, cursor, eidx);

    edge_kernel<<<EDGES/EB, NTHREADS, 0, stream>>>(
        xa, xv, xd, rij, BP, src, dst, eidx, (float*)d_out);
}

// Round 8
// 516.461 us; speedup vs baseline: 64.8621x; 1.2235x over previous
//
#include <hip/hip_runtime.h>

#define NODES    16384
#define EDGES    262144
#define OUT_CH   304      // 64 + 32*3 + 16*9
#define EB       16       // edges per block
#define NTHREADS 256

typedef __attribute__((ext_vector_type(8))) short short8;
typedef __attribute__((ext_vector_type(4))) float f32x4;
typedef __attribute__((ext_vector_type(8))) float f32x8;
typedef __attribute__((ext_vector_type(8))) __bf16 bf16x8;
#define MFMA(a,b,c) __builtin_amdgcn_mfma_f32_16x16x32_bf16((a),(b),(c),0,0,0)

// ---------- packed-B (bf16) sizes ----------
// B1: K=896 (BW=112), 7 N-tiles  -> 28*7*64*8 = 100352 ushort
// B2: K=768 (BW=96),  3 N-tiles  -> 24*3*64*8 =  36864 ushort
// B3: K=128 (BW=16),  1 N-tile   ->  4*1*64*8 =   2048 ushort
#define NB1 100352
#define NB2 36864
#define NB3 2048
#define NPACK (NB1 + NB2 + NB3)     // 139264 ushort = 278528 B

// ---------------- fused prepack(B) + count kernel ----------------
__global__ __launch_bounds__(256) void prep_kernel(
    const float* __restrict__ P000, const float* __restrict__ P110, const float* __restrict__ P220,
    const float* __restrict__ P011, const float* __restrict__ P101, const float* __restrict__ P121,
    const float* __restrict__ P211, const float* __restrict__ P111,
    const float* __restrict__ P022, const float* __restrict__ P112, const float* __restrict__ P202,
    const float* __restrict__ P222, const float* __restrict__ P212,
    unsigned short* __restrict__ BP,
    const int* __restrict__ dst, int* __restrict__ cnt)
{
    int idx = blockIdx.x*256 + threadIdx.x;
    if (idx < NPACK) {
        float v = 0.0f;
        if (idx < NB1) {                       // GEMM1: BW=112
            int j = idx & 7, lane = (idx >> 3) & 63, q = idx >> 9;
            int tile = q % 7, kk = q / 7;
            int n = tile*16 + (lane & 15);
            int k = kk*32 + (lane >> 4)*8 + j;
            int l = k / 112, b = k % 112;
            if (n < 64) {           int c = n;
                if      (b <  64) v = P000[(c*8+l)*64 + b];
                else if (b <  96) v = P110[(c*8+l)*32 + (b-64)];
                else              v = P220[(c*8+l)*16 + (b-96)];
            } else if (n < 96) {    int c = n - 64;      // as0
                if      (b <  64) v = P101[(c*8+l)*64 + b];
                else if (b <  96) v = P211[(c*8+l)*32 + (b-64)];
            } else {                int c = n - 96;      // a00
                if      (b <  64) v = P202[(c*8+l)*64 + b];
            }
        } else if (idx < NB1 + NB2) {          // GEMM2: BW=96
            int o = idx - NB1;
            int j = o & 7, lane = (o >> 3) & 63, q = o >> 9;
            int tile = q % 3, kk = q / 3;
            int n = tile*16 + (lane & 15);
            int k = kk*32 + (lane >> 4)*8 + j;
            int l = k / 96, b = k % 96;
            if (n < 32) {           int c = n;           // av
                if      (b <  32) v = P011[(c*8+l)*32 + b];
                else if (b <  48) v = P121[(c*8+l)*16 + (b-32)];
                else if (b <  80) v = P111[(c*8+l)*32 + (b-48)];
            } else {                int c = n - 32;      // aj
                if      (b <  32) v = P112[(c*8+l)*32 + b];
                else if (b <  48) v = 0.0f;
                else if (b <  80) v = P212[(c*8+l)*32 + (b-48)];
                else              v = P222[(c*8+l)*16 + (b-80)];
            }
        } else {                               // GEMM3: BW=16
            int o = idx - NB1 - NB2;
            int j = o & 7, lane = (o >> 3) & 63, kk = o >> 9;
            int n = lane & 15;
            int k = kk*32 + (lane >> 4)*8 + j;
            int l = k / 16, b = k % 16;
            v = P022[(n*8+l)*16 + b];
        }
        union { float f; unsigned int i; } x; x.f = v;
        unsigned int i = x.i;
        i += 0x7fffu + ((i >> 16) & 1u);
        BP[idx] = (unsigned short)(i >> 16);
    }
    if (idx < EDGES) atomicAdd(&cnt[dst[idx]], 1);
}

// ---------------- CSR scan + scatter (verified) ----------------
__global__ __launch_bounds__(256) void scan_kernel(const int* __restrict__ cnt,
                                                   int* __restrict__ off,
                                                   int* __restrict__ cursor)
{
    __shared__ int s_part[256];
    const int t = threadIdx.x;
    const int base = t * 64;
    int sum = 0;
    for (int i = 0; i < 64; ++i) sum += cnt[base + i];
    s_part[t] = sum;
    __syncthreads();
    for (int d = 1; d < 256; d <<= 1) {
        int add = (t >= d) ? s_part[t - d] : 0;
        __syncthreads();
        s_part[t] += add;
        __syncthreads();
    }
    int run = s_part[t] - sum;
    for (int i = 0; i < 64; ++i) {
        int c = cnt[base + i];
        off[base + i]    = run;
        cursor[base + i] = run;
        run += c;
    }
    if (t == 255) off[NODES] = run;
}

__global__ __launch_bounds__(256) void scatter_kernel(const int* __restrict__ dst,
                                                      int* __restrict__ cursor,
                                                      int* __restrict__ eidx)
{
    int e = blockIdx.x*256 + threadIdx.x;
    if (e < EDGES) {
        int pos = atomicAdd(&cursor[dst[e]], 1);
        eidx[pos] = e;
    }
}

// A-fragment on the fly: lane holds z[m][k..k+7], z = rad[l]*feat[b]
// packed mul + packed RNE bf16 convert (fptrunc) — no scalar int rounding.
template<int BW>
__device__ __forceinline__ short8 build_afrag(const float* __restrict__ frow,
                                              const float* __restrict__ radrow,
                                              int kbase)
{
    const int l  = kbase / BW;
    const int b0 = kbase % BW;            // multiple of 8
    const float r = radrow[l];
    union { float4 q[2]; f32x8 v; } u;
    u.q[0] = *reinterpret_cast<const float4*>(frow + b0);
    u.q[1] = *reinterpret_cast<const float4*>(frow + b0 + 4);
    f32x8 z = u.v * r;
    bf16x8 zb = __builtin_convertvector(z, bf16x8);
    union { bf16x8 b; short8 s; } w; w.b = zb;
    return w.s;
}

// ---------------- main edge kernel: MFMA, bank-uniform LDS ----------------
__global__ __launch_bounds__(NTHREADS, 2) void edge_kernel(
    const float* __restrict__ xa_g, const float* __restrict__ xv_g, const float* __restrict__ xd_g,
    const float* __restrict__ rij_g,
    const unsigned short* __restrict__ BP,
    const int* __restrict__ src, const int* __restrict__ dst, const int* __restrict__ eidx,
    float* __restrict__ out)
{
    // stride choices: (col*stride + quad*8) mod 32 spreads uniformly over banks
    __shared__ __align__(16) float s_FS [EB][116];     // xa[0,64) sv[64,96) sd[96,112)
    __shared__ __align__(16) float s_FVT[EB][3][100];  // [i][b]: xv[0,32) uv[32,48) cr[48,80) wd[80,96)
    __shared__ __align__(16) float s_FDT[EB][9][20];   // [ij][b<16]
    __shared__ float s_m[EB][308];
    __shared__ float s_as0[EB][32];
    __shared__ float s_a00[EB][16];
    __shared__ float s_aj[EB][3][16];
    __shared__ float s_rad[EB][9];
    __shared__ float s_rh[EB][4];
    __shared__ int   s_dst[EB];
    __shared__ int   s_srcn[EB];

    const int t  = threadIdx.x;
    const int e0 = blockIdx.x * EB;
    const int lane = t & 63, wid = t >> 6;
    const int col = lane & 15, quad = lane >> 4;

    const short8* __restrict__ B1 = (const short8*)BP;
    const short8* __restrict__ B2 = (const short8*)(BP + NB1);
    const short8* __restrict__ B3 = (const short8*)(BP + NB1 + NB2);

    // ---- phase 1a: per-edge radial basis + rh ----
    if (t < EB) {
        const int e = eidx[e0 + t];            // CSR order: s_dst non-decreasing
        float r0 = rij_g[e*3+0];
        float r1 = rij_g[e*3+1];
        float r2 = rij_g[e*3+2];
        float x_sq = (r0*r0 + r1*r1 + r2*r2) * 0.125f;
        float q  = sqrtf(x_sq);
        float w  = fmaxf(1.0f - x_sq, 0.0f);
        const float PI = 3.14159265358979323846f;
        for (int n = 0; n < 8; ++n)
            s_rad[t][n] = cosf(PI * (float)n * q) * w;
        float y0 = r0*0.875f, y1 = r1*0.875f, y2 = r2*0.875f;
        float nn = sqrtf(y0*y0 + y1*y1 + y2*y2);
        float sc = tanhf(nn) / fmaxf(nn, 1e-6f);
        s_rh[t][0] = y0*sc; s_rh[t][1] = y1*sc; s_rh[t][2] = y2*sc; s_rh[t][3] = 0.f;
        s_dst[t]  = dst[e];
        s_srcn[t] = src[e];
    }
    __syncthreads();

    // ---- phase 1b: gather node features into LDS (verified math, padded layout) ----
    {
        const int el  = t >> 4;
        const int sub = t & 15;
        const int n   = s_srcn[el];
        const float rh0 = s_rh[el][0], rh1 = s_rh[el][1], rh2 = s_rh[el][2];
        #pragma unroll
        for (int k = 0; k < 4; ++k) {
            int b = sub + 16*k;
            s_FS[el][b] = xa_g[n*64 + b];
        }
        #pragma unroll
        for (int k = 0; k < 2; ++k) {
            int b = sub + 16*k;
            float v0 = xv_g[(n*32 + b)*3 + 0];
            float v1 = xv_g[(n*32 + b)*3 + 1];
            float v2 = xv_g[(n*32 + b)*3 + 2];
            s_FVT[el][0][b] = v0;
            s_FVT[el][1][b] = v1;
            s_FVT[el][2][b] = v2;
            s_FS[el][64 + b] = rh0*v0 + rh1*v1 + rh2*v2;          // sv
            s_FVT[el][0][48 + b] = rh1*v2 - rh2*v1;               // cr
            s_FVT[el][1][48 + b] = rh2*v0 - rh0*v2;
            s_FVT[el][2][48 + b] = rh0*v1 - rh1*v0;
        }
        {
            const int b = sub;
            const float d0 = xd_g[(n*16+b)*9+0], d1 = xd_g[(n*16+b)*9+1], d2 = xd_g[(n*16+b)*9+2];
            const float d3 = xd_g[(n*16+b)*9+3], d4 = xd_g[(n*16+b)*9+4], d5 = xd_g[(n*16+b)*9+5];
            const float d6 = xd_g[(n*16+b)*9+6], d7 = xd_g[(n*16+b)*9+7], d8 = xd_g[(n*16+b)*9+8];
            s_FDT[el][0][b]=d0; s_FDT[el][1][b]=d1; s_FDT[el][2][b]=d2;
            s_FDT[el][3][b]=d3; s_FDT[el][4][b]=d4; s_FDT[el][5][b]=d5;
            s_FDT[el][6][b]=d6; s_FDT[el][7][b]=d7; s_FDT[el][8][b]=d8;
            const float uv0 = d0*rh0 + d1*rh1 + d2*rh2;
            const float uv1 = d3*rh0 + d4*rh1 + d5*rh2;
            const float uv2 = d6*rh0 + d7*rh1 + d8*rh2;
            s_FVT[el][0][32 + b] = uv0;
            s_FVT[el][1][32 + b] = uv1;
            s_FVT[el][2][32 + b] = uv2;
            s_FVT[el][0][80 + b] = rh0*d0 + rh1*d3 + rh2*d6;      // wd
            s_FVT[el][1][80 + b] = rh0*d1 + rh1*d4 + rh2*d7;
            s_FVT[el][2][80 + b] = rh0*d2 + rh1*d5 + rh2*d8;
            s_FS[el][96 + b] = rh0*uv0 + rh1*uv1 + rh2*uv2;       // sd
        }
    }
    __syncthreads();

    // ---- GEMM phase: wave-split MFMA.  D row = quad*4+reg (edge), col = lane&15 (chan) ----
    const float* __restrict__ radrow = &s_rad[col][0];
    const int r0 = quad*4;

    if (wid == 0) {
        // z_A x {m_a cols 0..63}; then GEMM3 ij 0..3
        const float* frow = &s_FS[col][0];
        f32x4 c0 = {0,0,0,0}, c1 = {0,0,0,0}, c2 = {0,0,0,0}, c3 = {0,0,0,0};
        for (int kk = 0; kk < 28; ++kk) {
            short8 a = build_afrag<112>(frow, radrow, kk*32 + quad*8);
            const short8* bp = B1 + (kk*7)*64 + lane;
            c0 = MFMA(a, bp[0*64], c0);
            c1 = MFMA(a, bp[1*64], c1);
            c2 = MFMA(a, bp[2*64], c2);
            c3 = MFMA(a, bp[3*64], c3);
        }
        #pragma unroll
        for (int r = 0; r < 4; ++r) {
            s_m[r0+r][ 0+col] = c0[r];
            s_m[r0+r][16+col] = c1[r];
            s_m[r0+r][32+col] = c2[r];
            s_m[r0+r][48+col] = c3[r];
        }
        for (int ij = 0; ij < 4; ++ij) {
            const float* fd = &s_FDT[col][ij][0];
            f32x4 d = {0,0,0,0};
            #pragma unroll
            for (int kk = 0; kk < 4; ++kk) {
                short8 a = build_afrag<16>(fd, radrow, kk*32 + quad*8);
                d = MFMA(a, B3[kk*64 + lane], d);
            }
            #pragma unroll
            for (int r = 0; r < 4; ++r)
                s_m[r0+r][160 + col*9 + ij] = d[r];
        }
    } else if (wid == 1) {
        // z_A x {as0 (tiles 4,5), a00 (tile 6)}; then GEMM3 ij 4..8
        const float* frow = &s_FS[col][0];
        f32x4 c4 = {0,0,0,0}, c5 = {0,0,0,0}, c6 = {0,0,0,0};
        for (int kk = 0; kk < 28; ++kk) {
            short8 a = build_afrag<112>(frow, radrow, kk*32 + quad*8);
            const short8* bp = B1 + (kk*7)*64 + lane;
            c4 = MFMA(a, bp[4*64], c4);
            c5 = MFMA(a, bp[5*64], c5);
            c6 = MFMA(a, bp[6*64], c6);
        }
        #pragma unroll
        for (int r = 0; r < 4; ++r) {
            s_as0[r0+r][ 0+col] = c4[r];
            s_as0[r0+r][16+col] = c5[r];
            s_a00[r0+r][col]    = c6[r];
        }
        for (int ij = 4; ij < 9; ++ij) {
            const float* fd = &s_FDT[col][ij][0];
            f32x4 d = {0,0,0,0};
            #pragma unroll
            for (int kk = 0; kk < 4; ++kk) {
                short8 a = build_afrag<16>(fd, radrow, kk*32 + quad*8);
                d = MFMA(a, B3[kk*64 + lane], d);
            }
            #pragma unroll
            for (int r = 0; r < 4; ++r)
                s_m[r0+r][160 + col*9 + ij] = d[r];
        }
    } else if (wid == 2) {
        // z_V^0 x {av0 t0,t1; aj0 t2}; z_V^1 x {av1 t0,t1}
        const float* f0 = &s_FVT[col][0][0];
        const float* f1 = &s_FVT[col][1][0];
        f32x4 c00={0,0,0,0}, c01={0,0,0,0}, c02={0,0,0,0}, c10={0,0,0,0}, c11={0,0,0,0};
        for (int kk = 0; kk < 24; ++kk) {
            short8 a0 = build_afrag<96>(f0, radrow, kk*32 + quad*8);
            short8 a1 = build_afrag<96>(f1, radrow, kk*32 + quad*8);
            const short8* bp = B2 + (kk*3)*64 + lane;
            short8 b0 = bp[0*64], b1 = bp[1*64], b2 = bp[2*64];
            c00 = MFMA(a0, b0, c00);
            c01 = MFMA(a0, b1, c01);
            c02 = MFMA(a0, b2, c02);
            c10 = MFMA(a1, b0, c10);
            c11 = MFMA(a1, b1, c11);
        }
        #pragma unroll
        for (int r = 0; r < 4; ++r) {
            s_m[r0+r][64 + ( 0+col)*3 + 0] = c00[r];
            s_m[r0+r][64 + (16+col)*3 + 0] = c01[r];
            s_aj[r0+r][0][col]             = c02[r];
            s_m[r0+r][64 + ( 0+col)*3 + 1] = c10[r];
            s_m[r0+r][64 + (16+col)*3 + 1] = c11[r];
        }
    } else {
        // z_V^1 x {aj1 t2}; z_V^2 x {av2 t0,t1; aj2 t2}
        const float* f1 = &s_FVT[col][1][0];
        const float* f2 = &s_FVT[col][2][0];
        f32x4 c12={0,0,0,0}, c20={0,0,0,0}, c21={0,0,0,0}, c22={0,0,0,0};
        for (int kk = 0; kk < 24; ++kk) {
            short8 a1 = build_afrag<96>(f1, radrow, kk*32 + quad*8);
            short8 a2 = build_afrag<96>(f2, radrow, kk*32 + quad*8);
            const short8* bp = B2 + (kk*3)*64 + lane;
            short8 b0 = bp[0*64], b1 = bp[1*64], b2 = bp[2*64];
            c12 = MFMA(a1, b2, c12);
            c20 = MFMA(a2, b0, c20);
            c21 = MFMA(a2, b1, c21);
            c22 = MFMA(a2, b2, c22);
        }
        #pragma unroll
        for (int r = 0; r < 4; ++r) {
            s_aj[r0+r][1][col]             = c12[r];
            s_m[r0+r][64 + ( 0+col)*3 + 2] = c20[r];
            s_m[r0+r][64 + (16+col)*3 + 2] = c21[r];
            s_aj[r0+r][2][col]             = c22[r];
        }
    }
    __syncthreads();

    // ---- combine: recouple rh factors ----
    #pragma unroll
    for (int it = t; it < EB*32; it += NTHREADS) {
        const int el = it >> 5, c = it & 31;
        const float as0 = s_as0[el][c];
        s_m[el][64 + c*3 + 0] += s_rh[el][0]*as0;
        s_m[el][64 + c*3 + 1] += s_rh[el][1]*as0;
        s_m[el][64 + c*3 + 2] += s_rh[el][2]*as0;
    }
    {
        const int el = t >> 4, c = t & 15;
        const float a00 = s_a00[el][c];
        const float aj0 = s_aj[el][0][c], aj1 = s_aj[el][1][c], aj2 = s_aj[el][2][c];
        const float rr0 = s_rh[el][0], rr1 = s_rh[el][1], rr2 = s_rh[el][2];
        const float g0 = aj0 + rr0*a00, g1 = aj1 + rr1*a00, g2 = aj2 + rr2*a00;
        float* md = &s_m[el][160 + c*9];
        md[0] += rr0*g0; md[1] += rr0*g1; md[2] += rr0*g2;
        md[3] += rr1*g0; md[4] += rr1*g1; md[5] += rr1*g2;
        md[6] += rr2*g0; md[7] += rr2*g1; md[8] += rr2*g2;
    }
    __syncthreads();

    // ---- segmented emit: s_dst non-decreasing -> one atomic per (segment, channel) ----
    for (int ch = t; ch < OUT_CH; ch += NTHREADS) {
        float run = 0.0f;
        #pragma unroll
        for (int el = 0; el < EB; ++el) {
            run += s_m[el][ch];
            if (el == EB-1 || s_dst[el+1] != s_dst[el]) {
                atomicAdd(&out[(size_t)s_dst[el]*OUT_CH + ch], run);
                run = 0.0f;
            }
        }
    }
}

extern "C" void kernel_launch(void* const* d_in, const int* in_sizes, int n_in,
                              void* d_out, int out_size, void* d_ws, size_t ws_size,
                              hipStream_t stream)
{
    const float* xa  = (const float*)d_in[0];
    const float* xv  = (const float*)d_in[1];
    const float* xd  = (const float*)d_in[2];
    const float* rij = (const float*)d_in[3];
    const float* P000 = (const float*)d_in[4];
    const float* P110 = (const float*)d_in[5];
    const float* P220 = (const float*)d_in[6];
    const float* P011 = (const float*)d_in[7];
    const float* P101 = (const float*)d_in[8];
    const float* P121 = (const float*)d_in[9];
    const float* P211 = (const float*)d_in[10];
    const float* P111 = (const float*)d_in[11];
    const float* P022 = (const float*)d_in[12];
    const float* P112 = (const float*)d_in[13];
    const float* P202 = (const float*)d_in[14];
    const float* P222 = (const float*)d_in[15];
    const float* P212 = (const float*)d_in[16];
    const int* src = (const int*)d_in[17];
    const int* dst = (const int*)d_in[18];

    unsigned short* BP = (unsigned short*)d_ws;
    int* ip     = (int*)d_ws + (NPACK/2);
    int* cnt    = ip;
    int* off    = ip + NODES;
    int* cursor = off + NODES + 1;
    int* eidx   = cursor + NODES;

    hipMemsetAsync(cnt, 0, NODES * sizeof(int), stream);
    hipMemsetAsync(d_out, 0, (size_t)out_size * sizeof(float), stream);

    prep_kernel<<<EDGES/256, 256, 0, stream>>>(
        P000, P110, P220, P011, P101, P121, P211, P111,
        P022, P112, P202, P222, P212, BP, dst, cnt);
    scan_kernel   <<<1,         256, 0, stream>>>(cnt, off, cursor);
    scatter_kernel<<<EDGES/256, 256, 0, stream>>>(dst, cursor, eidx);

    edge_kernel<<<EDGES/EB, NTHREADS, 0, stream>>>(
        xa, xv, xd, rij, BP, src, dst, eidx, (float*)d_out);
}

// Round 9
// 447.026 us; speedup vs baseline: 74.9368x; 1.1553x over previous
//
#include <hip/hip_runtime.h>

#define NODES    16384
#define EDGES    262144
#define OUT_CH   304      // 64 + 32*3 + 16*9
#define EB       16       // edges per block
#define NTHREADS 256

typedef __attribute__((ext_vector_type(8))) short short8;
typedef __attribute__((ext_vector_type(4))) float f32x4;
typedef __attribute__((ext_vector_type(8))) float f32x8;
typedef __attribute__((ext_vector_type(8))) __bf16 bf16x8;
#define MFMA(a,b,c) __builtin_amdgcn_mfma_f32_16x16x32_bf16((a),(b),(c),0,0,0)

// ---------- packed-B (bf16) sizes ----------
#define NB1 100352
#define NB2 36864
#define NB3 2048
#define NPACK (NB1 + NB2 + NB3)     // 139264 ushort = 278528 B

// ---------------- fused prepack(B) + count kernel ----------------
__global__ __launch_bounds__(256) void prep_kernel(
    const float* __restrict__ P000, const float* __restrict__ P110, const float* __restrict__ P220,
    const float* __restrict__ P011, const float* __restrict__ P101, const float* __restrict__ P121,
    const float* __restrict__ P211, const float* __restrict__ P111,
    const float* __restrict__ P022, const float* __restrict__ P112, const float* __restrict__ P202,
    const float* __restrict__ P222, const float* __restrict__ P212,
    unsigned short* __restrict__ BP,
    const int* __restrict__ dst, int* __restrict__ cnt)
{
    int idx = blockIdx.x*256 + threadIdx.x;
    if (idx < NPACK) {
        float v = 0.0f;
        if (idx < NB1) {                       // GEMM1: BW=112
            int j = idx & 7, lane = (idx >> 3) & 63, q = idx >> 9;
            int tile = q % 7, kk = q / 7;
            int n = tile*16 + (lane & 15);
            int k = kk*32 + (lane >> 4)*8 + j;
            int l = k / 112, b = k % 112;
            if (n < 64) {           int c = n;
                if      (b <  64) v = P000[(c*8+l)*64 + b];
                else if (b <  96) v = P110[(c*8+l)*32 + (b-64)];
                else              v = P220[(c*8+l)*16 + (b-96)];
            } else if (n < 96) {    int c = n - 64;      // as0
                if      (b <  64) v = P101[(c*8+l)*64 + b];
                else if (b <  96) v = P211[(c*8+l)*32 + (b-64)];
            } else {                int c = n - 96;      // a00
                if      (b <  64) v = P202[(c*8+l)*64 + b];
            }
        } else if (idx < NB1 + NB2) {          // GEMM2: BW=96
            int o = idx - NB1;
            int j = o & 7, lane = (o >> 3) & 63, q = o >> 9;
            int tile = q % 3, kk = q / 3;
            int n = tile*16 + (lane & 15);
            int k = kk*32 + (lane >> 4)*8 + j;
            int l = k / 96, b = k % 96;
            if (n < 32) {           int c = n;           // av
                if      (b <  32) v = P011[(c*8+l)*32 + b];
                else if (b <  48) v = P121[(c*8+l)*16 + (b-32)];
                else if (b <  80) v = P111[(c*8+l)*32 + (b-48)];
            } else {                int c = n - 32;      // aj
                if      (b <  32) v = P112[(c*8+l)*32 + b];
                else if (b <  48) v = 0.0f;
                else if (b <  80) v = P212[(c*8+l)*32 + (b-48)];
                else              v = P222[(c*8+l)*16 + (b-80)];
            }
        } else {                               // GEMM3: BW=16
            int o = idx - NB1 - NB2;
            int j = o & 7, lane = (o >> 3) & 63, kk = o >> 9;
            int n = lane & 15;
            int k = kk*32 + (lane >> 4)*8 + j;
            int l = k / 16, b = k % 16;
            v = P022[(n*8+l)*16 + b];
        }
        union { float f; unsigned int i; } x; x.f = v;
        unsigned int i = x.i;
        i += 0x7fffu + ((i >> 16) & 1u);
        BP[idx] = (unsigned short)(i >> 16);
    }
    if (idx < EDGES) atomicAdd(&cnt[dst[idx]], 1);
}

// ---------------- CSR scan + scatter (verified) ----------------
__global__ __launch_bounds__(256) void scan_kernel(const int* __restrict__ cnt,
                                                   int* __restrict__ off,
                                                   int* __restrict__ cursor)
{
    __shared__ int s_part[256];
    const int t = threadIdx.x;
    const int base = t * 64;
    int sum = 0;
    for (int i = 0; i < 64; ++i) sum += cnt[base + i];
    s_part[t] = sum;
    __syncthreads();
    for (int d = 1; d < 256; d <<= 1) {
        int add = (t >= d) ? s_part[t - d] : 0;
        __syncthreads();
        s_part[t] += add;
        __syncthreads();
    }
    int run = s_part[t] - sum;
    for (int i = 0; i < 64; ++i) {
        int c = cnt[base + i];
        off[base + i]    = run;
        cursor[base + i] = run;
        run += c;
    }
    if (t == 255) off[NODES] = run;
}

__global__ __launch_bounds__(256) void scatter_kernel(const int* __restrict__ dst,
                                                      int* __restrict__ cursor,
                                                      int* __restrict__ eidx)
{
    int e = blockIdx.x*256 + threadIdx.x;
    if (e < EDGES) {
        int pos = atomicAdd(&cursor[dst[e]], 1);
        eidx[pos] = e;
    }
}

// A-fragment on the fly: z = rad[l]*feat[b], packed mul + packed RNE bf16 cvt
template<int BW>
__device__ __forceinline__ short8 build_afrag(const float* __restrict__ frow,
                                              const float* __restrict__ radrow,
                                              int kbase)
{
    const int l  = kbase / BW;
    const int b0 = kbase % BW;            // multiple of 8
    const float r = radrow[l];
    union { float4 q[2]; f32x8 v; } u;
    u.q[0] = *reinterpret_cast<const float4*>(frow + b0);
    u.q[1] = *reinterpret_cast<const float4*>(frow + b0 + 4);
    f32x8 z = u.v * r;
    bf16x8 zb = __builtin_convertvector(z, bf16x8);
    union { bf16x8 b; short8 s; } w; w.b = zb;
    return w.s;
}

// feature pool (dead after GEMM loops) unioned with message staging
struct FeatPool {
    float FS[EB][116];       // xa[0,64) sv[64,96) sd[96,112)
    float FVT[EB][3][100];   // [i][b]: xv[0,32) uv[32,48) cr[48,80) wd[80,96)
};
union Pool {
    FeatPool f;              // 26624 B
    float m[EB][308];        // 19712 B
};

// ---------------- main edge kernel: MFMA, LDS-unioned for 3 blocks/CU ----------------
__global__ __launch_bounds__(NTHREADS, 3) void edge_kernel(
    const float* __restrict__ xa_g, const float* __restrict__ xv_g, const float* __restrict__ xd_g,
    const float* __restrict__ rij_g,
    const unsigned short* __restrict__ BP,
    const int* __restrict__ src, const int* __restrict__ dst, const int* __restrict__ eidx,
    float* __restrict__ out)
{
    __shared__ __align__(16) Pool s_p;
    __shared__ __align__(16) float s_FDT[EB][9][20];   // [ij][b<16]
    __shared__ float s_as0[EB][32];
    __shared__ float s_a00[EB][16];
    __shared__ float s_aj[EB][3][16];
    __shared__ float s_rad[EB][9];
    __shared__ float s_rh[EB][4];
    __shared__ int   s_dst[EB];
    __shared__ int   s_srcn[EB];

    const int t  = threadIdx.x;
    const int e0 = blockIdx.x * EB;
    const int lane = t & 63, wid = t >> 6;
    const int col = lane & 15, quad = lane >> 4;

    const short8* __restrict__ B1 = (const short8*)BP;
    const short8* __restrict__ B2 = (const short8*)(BP + NB1);
    const short8* __restrict__ B3 = (const short8*)(BP + NB1 + NB2);

    // ---- phase 1a: per-edge radial basis + rh ----
    if (t < EB) {
        const int e = eidx[e0 + t];            // CSR order: s_dst non-decreasing
        float r0 = rij_g[e*3+0];
        float r1 = rij_g[e*3+1];
        float r2 = rij_g[e*3+2];
        float x_sq = (r0*r0 + r1*r1 + r2*r2) * 0.125f;
        float q  = sqrtf(x_sq);
        float w  = fmaxf(1.0f - x_sq, 0.0f);
        const float PI = 3.14159265358979323846f;
        for (int n = 0; n < 8; ++n)
            s_rad[t][n] = cosf(PI * (float)n * q) * w;
        float y0 = r0*0.875f, y1 = r1*0.875f, y2 = r2*0.875f;
        float nn = sqrtf(y0*y0 + y1*y1 + y2*y2);
        float sc = tanhf(nn) / fmaxf(nn, 1e-6f);
        s_rh[t][0] = y0*sc; s_rh[t][1] = y1*sc; s_rh[t][2] = y2*sc; s_rh[t][3] = 0.f;
        s_dst[t]  = dst[e];
        s_srcn[t] = src[e];
    }
    __syncthreads();

    // ---- phase 1b: gather node features into LDS (verified math/layout) ----
    {
        const int el  = t >> 4;
        const int sub = t & 15;
        const int n   = s_srcn[el];
        const float rh0 = s_rh[el][0], rh1 = s_rh[el][1], rh2 = s_rh[el][2];
        #pragma unroll
        for (int k = 0; k < 4; ++k) {
            int b = sub + 16*k;
            s_p.f.FS[el][b] = xa_g[n*64 + b];
        }
        #pragma unroll
        for (int k = 0; k < 2; ++k) {
            int b = sub + 16*k;
            float v0 = xv_g[(n*32 + b)*3 + 0];
            float v1 = xv_g[(n*32 + b)*3 + 1];
            float v2 = xv_g[(n*32 + b)*3 + 2];
            s_p.f.FVT[el][0][b] = v0;
            s_p.f.FVT[el][1][b] = v1;
            s_p.f.FVT[el][2][b] = v2;
            s_p.f.FS[el][64 + b] = rh0*v0 + rh1*v1 + rh2*v2;      // sv
            s_p.f.FVT[el][0][48 + b] = rh1*v2 - rh2*v1;           // cr
            s_p.f.FVT[el][1][48 + b] = rh2*v0 - rh0*v2;
            s_p.f.FVT[el][2][48 + b] = rh0*v1 - rh1*v0;
        }
        {
            const int b = sub;
            const float d0 = xd_g[(n*16+b)*9+0], d1 = xd_g[(n*16+b)*9+1], d2 = xd_g[(n*16+b)*9+2];
            const float d3 = xd_g[(n*16+b)*9+3], d4 = xd_g[(n*16+b)*9+4], d5 = xd_g[(n*16+b)*9+5];
            const float d6 = xd_g[(n*16+b)*9+6], d7 = xd_g[(n*16+b)*9+7], d8 = xd_g[(n*16+b)*9+8];
            s_FDT[el][0][b]=d0; s_FDT[el][1][b]=d1; s_FDT[el][2][b]=d2;
            s_FDT[el][3][b]=d3; s_FDT[el][4][b]=d4; s_FDT[el][5][b]=d5;
            s_FDT[el][6][b]=d6; s_FDT[el][7][b]=d7; s_FDT[el][8][b]=d8;
            const float uv0 = d0*rh0 + d1*rh1 + d2*rh2;
            const float uv1 = d3*rh0 + d4*rh1 + d5*rh2;
            const float uv2 = d6*rh0 + d7*rh1 + d8*rh2;
            s_p.f.FVT[el][0][32 + b] = uv0;
            s_p.f.FVT[el][1][32 + b] = uv1;
            s_p.f.FVT[el][2][32 + b] = uv2;
            s_p.f.FVT[el][0][80 + b] = rh0*d0 + rh1*d3 + rh2*d6;  // wd
            s_p.f.FVT[el][1][80 + b] = rh0*d1 + rh1*d4 + rh2*d7;
            s_p.f.FVT[el][2][80 + b] = rh0*d2 + rh1*d5 + rh2*d8;
            s_p.f.FS[el][96 + b] = rh0*uv0 + rh1*uv1 + rh2*uv2;   // sd
        }
    }
    __syncthreads();

    // ---- GEMM phase: accumulate in registers only (feature pool stays live) ----
    const float* __restrict__ radrow = &s_rad[col][0];
    const int r0 = quad*4;
    f32x4 R0={0,0,0,0}, R1={0,0,0,0}, R2={0,0,0,0}, R3={0,0,0,0};
    f32x4 R4={0,0,0,0}, R5={0,0,0,0}, R6={0,0,0,0}, R7={0,0,0,0};

    if (wid == 0) {
        // z_A x {m_a tiles 0-3} -> R0-3; GEMM3 ij 0-3 -> R4-7
        const float* frow = &s_p.f.FS[col][0];
        for (int kk = 0; kk < 28; ++kk) {
            short8 a = build_afrag<112>(frow, radrow, kk*32 + quad*8);
            const short8* bp = B1 + (kk*7)*64 + lane;
            R0 = MFMA(a, bp[0*64], R0);
            R1 = MFMA(a, bp[1*64], R1);
            R2 = MFMA(a, bp[2*64], R2);
            R3 = MFMA(a, bp[3*64], R3);
        }
        {
            const float* fd0 = &s_FDT[col][0][0];
            const float* fd1 = &s_FDT[col][1][0];
            const float* fd2 = &s_FDT[col][2][0];
            const float* fd3 = &s_FDT[col][3][0];
            #pragma unroll
            for (int kk = 0; kk < 4; ++kk) {
                const short8 b3 = B3[kk*64 + lane];
                R4 = MFMA(build_afrag<16>(fd0, radrow, kk*32 + quad*8), b3, R4);
                R5 = MFMA(build_afrag<16>(fd1, radrow, kk*32 + quad*8), b3, R5);
                R6 = MFMA(build_afrag<16>(fd2, radrow, kk*32 + quad*8), b3, R6);
                R7 = MFMA(build_afrag<16>(fd3, radrow, kk*32 + quad*8), b3, R7);
            }
        }
    } else if (wid == 1) {
        // z_A x {as0 t4,t5; a00 t6} -> R0-2; GEMM3 ij 4-8 -> R3-7
        const float* frow = &s_p.f.FS[col][0];
        for (int kk = 0; kk < 28; ++kk) {
            short8 a = build_afrag<112>(frow, radrow, kk*32 + quad*8);
            const short8* bp = B1 + (kk*7)*64 + lane;
            R0 = MFMA(a, bp[4*64], R0);
            R1 = MFMA(a, bp[5*64], R1);
            R2 = MFMA(a, bp[6*64], R2);
        }
        {
            const float* fd4 = &s_FDT[col][4][0];
            const float* fd5 = &s_FDT[col][5][0];
            const float* fd6 = &s_FDT[col][6][0];
            const float* fd7 = &s_FDT[col][7][0];
            const float* fd8 = &s_FDT[col][8][0];
            #pragma unroll
            for (int kk = 0; kk < 4; ++kk) {
                const short8 b3 = B3[kk*64 + lane];
                R3 = MFMA(build_afrag<16>(fd4, radrow, kk*32 + quad*8), b3, R3);
                R4 = MFMA(build_afrag<16>(fd5, radrow, kk*32 + quad*8), b3, R4);
                R5 = MFMA(build_afrag<16>(fd6, radrow, kk*32 + quad*8), b3, R5);
                R6 = MFMA(build_afrag<16>(fd7, radrow, kk*32 + quad*8), b3, R6);
                R7 = MFMA(build_afrag<16>(fd8, radrow, kk*32 + quad*8), b3, R7);
            }
        }
    } else if (wid == 2) {
        // z_V^0 x {av0 t0,t1; aj0 t2} -> R0,R1,R2; z_V^1 x {av1 t0,t1} -> R3,R4
        const float* f0 = &s_p.f.FVT[col][0][0];
        const float* f1 = &s_p.f.FVT[col][1][0];
        for (int kk = 0; kk < 24; ++kk) {
            short8 a0 = build_afrag<96>(f0, radrow, kk*32 + quad*8);
            short8 a1 = build_afrag<96>(f1, radrow, kk*32 + quad*8);
            const short8* bp = B2 + (kk*3)*64 + lane;
            short8 b0 = bp[0*64], b1 = bp[1*64], b2 = bp[2*64];
            R0 = MFMA(a0, b0, R0);
            R1 = MFMA(a0, b1, R1);
            R2 = MFMA(a0, b2, R2);
            R3 = MFMA(a1, b0, R3);
            R4 = MFMA(a1, b1, R4);
        }
    } else {
        // z_V^1 x {aj1 t2} -> R0; z_V^2 x {av2 t0,t1; aj2 t2} -> R1,R2,R3
        const float* f1 = &s_p.f.FVT[col][1][0];
        const float* f2 = &s_p.f.FVT[col][2][0];
        for (int kk = 0; kk < 24; ++kk) {
            short8 a1 = build_afrag<96>(f1, radrow, kk*32 + quad*8);
            short8 a2 = build_afrag<96>(f2, radrow, kk*32 + quad*8);
            const short8* bp = B2 + (kk*3)*64 + lane;
            short8 b0 = bp[0*64], b1 = bp[1*64], b2 = bp[2*64];
            R0 = MFMA(a1, b2, R0);
            R1 = MFMA(a2, b0, R1);
            R2 = MFMA(a2, b1, R2);
            R3 = MFMA(a2, b2, R3);
        }
    }
    __syncthreads();   // feature pool retires; s_m (aliased) becomes writable

    // ---- spill results to (unioned) message staging ----
    if (wid == 0) {
        #pragma unroll
        for (int r = 0; r < 4; ++r) {
            s_p.m[r0+r][ 0+col] = R0[r];
            s_p.m[r0+r][16+col] = R1[r];
            s_p.m[r0+r][32+col] = R2[r];
            s_p.m[r0+r][48+col] = R3[r];
            s_p.m[r0+r][160 + col*9 + 0] = R4[r];
            s_p.m[r0+r][160 + col*9 + 1] = R5[r];
            s_p.m[r0+r][160 + col*9 + 2] = R6[r];
            s_p.m[r0+r][160 + col*9 + 3] = R7[r];
        }
    } else if (wid == 1) {
        #pragma unroll
        for (int r = 0; r < 4; ++r) {
            s_as0[r0+r][ 0+col] = R0[r];
            s_as0[r0+r][16+col] = R1[r];
            s_a00[r0+r][col]    = R2[r];
            s_p.m[r0+r][160 + col*9 + 4] = R3[r];
            s_p.m[r0+r][160 + col*9 + 5] = R4[r];
            s_p.m[r0+r][160 + col*9 + 6] = R5[r];
            s_p.m[r0+r][160 + col*9 + 7] = R6[r];
            s_p.m[r0+r][160 + col*9 + 8] = R7[r];
        }
    } else if (wid == 2) {
        #pragma unroll
        for (int r = 0; r < 4; ++r) {
            s_p.m[r0+r][64 + ( 0+col)*3 + 0] = R0[r];
            s_p.m[r0+r][64 + (16+col)*3 + 0] = R1[r];
            s_aj[r0+r][0][col]               = R2[r];
            s_p.m[r0+r][64 + ( 0+col)*3 + 1] = R3[r];
            s_p.m[r0+r][64 + (16+col)*3 + 1] = R4[r];
        }
    } else {
        #pragma unroll
        for (int r = 0; r < 4; ++r) {
            s_aj[r0+r][1][col]               = R0[r];
            s_p.m[r0+r][64 + ( 0+col)*3 + 2] = R1[r];
            s_p.m[r0+r][64 + (16+col)*3 + 2] = R2[r];
            s_aj[r0+r][2][col]               = R3[r];
        }
    }
    __syncthreads();

    // ---- combine: recouple rh factors ----
    #pragma unroll
    for (int it = t; it < EB*32; it += NTHREADS) {
        const int el = it >> 5, c = it & 31;
        const float as0 = s_as0[el][c];
        s_p.m[el][64 + c*3 + 0] += s_rh[el][0]*as0;
        s_p.m[el][64 + c*3 + 1] += s_rh[el][1]*as0;
        s_p.m[el][64 + c*3 + 2] += s_rh[el][2]*as0;
    }
    {
        const int el = t >> 4, c = t & 15;
        const float a00 = s_a00[el][c];
        const float aj0 = s_aj[el][0][c], aj1 = s_aj[el][1][c], aj2 = s_aj[el][2][c];
        const float rr0 = s_rh[el][0], rr1 = s_rh[el][1], rr2 = s_rh[el][2];
        const float g0 = aj0 + rr0*a00, g1 = aj1 + rr1*a00, g2 = aj2 + rr2*a00;
        float* md = &s_p.m[el][160 + c*9];
        md[0] += rr0*g0; md[1] += rr0*g1; md[2] += rr0*g2;
        md[3] += rr1*g0; md[4] += rr1*g1; md[5] += rr1*g2;
        md[6] += rr2*g0; md[7] += rr2*g1; md[8] += rr2*g2;
    }
    __syncthreads();

    // ---- segmented emit: s_dst non-decreasing -> one atomic per (segment, channel) ----
    for (int ch = t; ch < OUT_CH; ch += NTHREADS) {
        float run = 0.0f;
        #pragma unroll
        for (int el = 0; el < EB; ++el) {
            run += s_p.m[el][ch];
            if (el == EB-1 || s_dst[el+1] != s_dst[el]) {
                atomicAdd(&out[(size_t)s_dst[el]*OUT_CH + ch], run);
                run = 0.0f;
            }
        }
    }
}

extern "C" void kernel_launch(void* const* d_in, const int* in_sizes, int n_in,
                              void* d_out, int out_size, void* d_ws, size_t ws_size,
                              hipStream_t stream)
{
    const float* xa  = (const float*)d_in[0];
    const float* xv  = (const float*)d_in[1];
    const float* xd  = (const float*)d_in[2];
    const float* rij = (const float*)d_in[3];
    const float* P000 = (const float*)d_in[4];
    const float* P110 = (const float*)d_in[5];
    const float* P220 = (const float*)d_in[6];
    const float* P011 = (const float*)d_in[7];
    const float* P101 = (const float*)d_in[8];
    const float* P121 = (const float*)d_in[9];
    const float* P211 = (const float*)d_in[10];
    const float* P111 = (const float*)d_in[11];
    const float* P022 = (const float*)d_in[12];
    const float* P112 = (const float*)d_in[13];
    const float* P202 = (const float*)d_in[14];
    const float* P222 = (const float*)d_in[15];
    const float* P212 = (const float*)d_in[16];
    const int* src = (const int*)d_in[17];
    const int* dst = (const int*)d_in[18];

    unsigned short* BP = (unsigned short*)d_ws;
    int* ip     = (int*)d_ws + (NPACK/2);
    int* cnt    = ip;
    int* off    = ip + NODES;
    int* cursor = off + NODES + 1;
    int* eidx   = cursor + NODES;

    hipMemsetAsync(cnt, 0, NODES * sizeof(int), stream);
    hipMemsetAsync(d_out, 0, (size_t)out_size * sizeof(float), stream);

    prep_kernel<<<EDGES/256, 256, 0, stream>>>(
        P000, P110, P220, P011, P101, P121, P211, P111,
        P022, P112, P202, P222, P212, BP, dst, cnt);
    scan_kernel   <<<1,         256, 0, stream>>>(cnt, off, cursor);
    scatter_kernel<<<EDGES/256, 256, 0, stream>>>(dst, cursor, eidx);

    edge_kernel<<<EDGES/EB, NTHREADS, 0, stream>>>(
        xa, xv, xd, rij, BP, src, dst, eidx, (float*)d_out);
}

// Round 10
// 407.610 us; speedup vs baseline: 82.1834x; 1.0967x over previous
//
#include <hip/hip_runtime.h>

#define NODES    16384
#define EDGES    262144
#define OUT_CH   304      // 64 + 32*3 + 16*9
#define EB       16       // edges per block
#define NTHREADS 256

typedef __attribute__((ext_vector_type(8))) short short8;
typedef __attribute__((ext_vector_type(4))) float f32x4;
typedef __attribute__((ext_vector_type(8))) float f32x8;
typedef __attribute__((ext_vector_type(8))) __bf16 bf16x8;
#define MFMA(a,b,c) __builtin_amdgcn_mfma_f32_16x16x32_bf16((a),(b),(c),0,0,0)

// ---------- packed-B (bf16) sizes ----------
#define NB1 100352
#define NB2 36864
#define NB3 2048
#define NPACK (NB1 + NB2 + NB3)     // 139264 ushort = 278528 B

// ---------------- fused prepack(B) + count kernel ----------------
// K-order: k = b*8 + l  (fragment of 8 consecutive k = one b, all 8 l)
__global__ __launch_bounds__(256) void prep_kernel(
    const float* __restrict__ P000, const float* __restrict__ P110, const float* __restrict__ P220,
    const float* __restrict__ P011, const float* __restrict__ P101, const float* __restrict__ P121,
    const float* __restrict__ P211, const float* __restrict__ P111,
    const float* __restrict__ P022, const float* __restrict__ P112, const float* __restrict__ P202,
    const float* __restrict__ P222, const float* __restrict__ P212,
    unsigned short* __restrict__ BP,
    const int* __restrict__ dst, int* __restrict__ cnt)
{
    int idx = blockIdx.x*256 + threadIdx.x;
    if (idx < NPACK) {
        float v = 0.0f;
        if (idx < NB1) {                       // GEMM1: BW=112
            int j = idx & 7, lane = (idx >> 3) & 63, q = idx >> 9;
            int tile = q % 7, kk = q / 7;
            int n = tile*16 + (lane & 15);
            int k = kk*32 + (lane >> 4)*8 + j;
            int l = k & 7, b = k >> 3;
            if (n < 64) {           int c = n;
                if      (b <  64) v = P000[(c*8+l)*64 + b];
                else if (b <  96) v = P110[(c*8+l)*32 + (b-64)];
                else              v = P220[(c*8+l)*16 + (b-96)];
            } else if (n < 96) {    int c = n - 64;      // as0
                if      (b <  64) v = P101[(c*8+l)*64 + b];
                else if (b <  96) v = P211[(c*8+l)*32 + (b-64)];
            } else {                int c = n - 96;      // a00
                if      (b <  64) v = P202[(c*8+l)*64 + b];
            }
        } else if (idx < NB1 + NB2) {          // GEMM2: BW=96
            int o = idx - NB1;
            int j = o & 7, lane = (o >> 3) & 63, q = o >> 9;
            int tile = q % 3, kk = q / 3;
            int n = tile*16 + (lane & 15);
            int k = kk*32 + (lane >> 4)*8 + j;
            int l = k & 7, b = k >> 3;
            if (n < 32) {           int c = n;           // av
                if      (b <  32) v = P011[(c*8+l)*32 + b];
                else if (b <  48) v = P121[(c*8+l)*16 + (b-32)];
                else if (b <  80) v = P111[(c*8+l)*32 + (b-48)];
            } else {                int c = n - 32;      // aj
                if      (b <  32) v = P112[(c*8+l)*32 + b];
                else if (b <  48) v = 0.0f;
                else if (b <  80) v = P212[(c*8+l)*32 + (b-48)];
                else              v = P222[(c*8+l)*16 + (b-80)];
            }
        } else {                               // GEMM3: BW=16
            int o = idx - NB1 - NB2;
            int j = o & 7, lane = (o >> 3) & 63, kk = o >> 9;
            int n = lane & 15;
            int k = kk*32 + (lane >> 4)*8 + j;
            int l = k & 7, b = k >> 3;
            v = P022[(n*8+l)*16 + b];
        }
        union { float f; unsigned int i; } x; x.f = v;
        unsigned int i = x.i;
        i += 0x7fffu + ((i >> 16) & 1u);
        BP[idx] = (unsigned short)(i >> 16);
    }
    if (idx < EDGES) atomicAdd(&cnt[dst[idx]], 1);
}

// ---------------- CSR scan + scatter (verified) ----------------
__global__ __launch_bounds__(256) void scan_kernel(const int* __restrict__ cnt,
                                                   int* __restrict__ off,
                                                   int* __restrict__ cursor)
{
    __shared__ int s_part[256];
    const int t = threadIdx.x;
    const int base = t * 64;
    int sum = 0;
    for (int i = 0; i < 64; ++i) sum += cnt[base + i];
    s_part[t] = sum;
    __syncthreads();
    for (int d = 1; d < 256; d <<= 1) {
        int add = (t >= d) ? s_part[t - d] : 0;
        __syncthreads();
        s_part[t] += add;
        __syncthreads();
    }
    int run = s_part[t] - sum;
    for (int i = 0; i < 64; ++i) {
        int c = cnt[base + i];
        off[base + i]    = run;
        cursor[base + i] = run;
        run += c;
    }
    if (t == 255) off[NODES] = run;
}

__global__ __launch_bounds__(256) void scatter_kernel(const int* __restrict__ dst,
                                                      int* __restrict__ cursor,
                                                      int* __restrict__ eidx)
{
    int e = blockIdx.x*256 + threadIdx.x;
    if (e < EDGES) {
        int pos = atomicAdd(&cursor[dst[e]], 1);
        eidx[pos] = e;
    }
}

// A-fragment: one feature element x the full (in-register) rad vector
__device__ __forceinline__ short8 build2(const f32x8 radv, float f)
{
    f32x8 z = radv * f;
    bf16x8 zb = __builtin_convertvector(z, bf16x8);
    union { bf16x8 b; short8 s; } w; w.b = zb;
    return w.s;
}

// feature pool (dead after GEMM loops) unioned with result staging
struct FeatPool {
    float FS[EB][116];       // xa[0,64) sv[64,96) sd[96,112)
    float FVT[EB][3][100];   // [i][b]: xv[0,32) uv[32,48) cr[48,80) wd[80,96)
};                           // 26624 B
struct MsgPool {
    float m[EB][308];        // 19712 B
    float as0[EB][32];       //  2048 B
    float a00[EB][16];       //  1024 B
    float aj[EB][3][16];     //  3072 B
};                           // 25856 B
union Pool {
    FeatPool f;
    MsgPool  g;
};

// ---------------- main edge kernel: MFMA, dword A-builds, 4 blocks/CU ----------------
__global__ __launch_bounds__(NTHREADS, 4) void edge_kernel(
    const float* __restrict__ xa_g, const float* __restrict__ xv_g, const float* __restrict__ xd_g,
    const float* __restrict__ rij_g,
    const unsigned short* __restrict__ BP,
    const int* __restrict__ src, const int* __restrict__ dst, const int* __restrict__ eidx,
    float* __restrict__ out)
{
    __shared__ __align__(16) Pool s_p;
    __shared__ __align__(16) float s_FDT[EB][9][20];   // [ij][b<16]
    __shared__ float s_rad[EB][9];
    __shared__ float s_rh[EB][4];
    __shared__ int   s_dst[EB];
    __shared__ int   s_srcn[EB];

    const int t  = threadIdx.x;
    const int e0 = blockIdx.x * EB;
    const int lane = t & 63, wid = t >> 6;
    const int col = lane & 15, quad = lane >> 4;

    const short8* __restrict__ B1 = (const short8*)BP;
    const short8* __restrict__ B2 = (const short8*)(BP + NB1);
    const short8* __restrict__ B3 = (const short8*)(BP + NB1 + NB2);

    // ---- phase 1a: per-edge radial basis + rh ----
    if (t < EB) {
        const int e = eidx[e0 + t];            // CSR order: s_dst non-decreasing
        float r0 = rij_g[e*3+0];
        float r1 = rij_g[e*3+1];
        float r2 = rij_g[e*3+2];
        float x_sq = (r0*r0 + r1*r1 + r2*r2) * 0.125f;
        float q  = sqrtf(x_sq);
        float w  = fmaxf(1.0f - x_sq, 0.0f);
        const float PI = 3.14159265358979323846f;
        for (int n = 0; n < 8; ++n)
            s_rad[t][n] = cosf(PI * (float)n * q) * w;
        float y0 = r0*0.875f, y1 = r1*0.875f, y2 = r2*0.875f;
        float nn = sqrtf(y0*y0 + y1*y1 + y2*y2);
        float sc = tanhf(nn) / fmaxf(nn, 1e-6f);
        s_rh[t][0] = y0*sc; s_rh[t][1] = y1*sc; s_rh[t][2] = y2*sc; s_rh[t][3] = 0.f;
        s_dst[t]  = dst[e];
        s_srcn[t] = src[e];
    }
    __syncthreads();

    // ---- phase 1b: gather node features into LDS (verified math/layout) ----
    {
        const int el  = t >> 4;
        const int sub = t & 15;
        const int n   = s_srcn[el];
        const float rh0 = s_rh[el][0], rh1 = s_rh[el][1], rh2 = s_rh[el][2];
        #pragma unroll
        for (int k = 0; k < 4; ++k) {
            int b = sub + 16*k;
            s_p.f.FS[el][b] = xa_g[n*64 + b];
        }
        #pragma unroll
        for (int k = 0; k < 2; ++k) {
            int b = sub + 16*k;
            float v0 = xv_g[(n*32 + b)*3 + 0];
            float v1 = xv_g[(n*32 + b)*3 + 1];
            float v2 = xv_g[(n*32 + b)*3 + 2];
            s_p.f.FVT[el][0][b] = v0;
            s_p.f.FVT[el][1][b] = v1;
            s_p.f.FVT[el][2][b] = v2;
            s_p.f.FS[el][64 + b] = rh0*v0 + rh1*v1 + rh2*v2;      // sv
            s_p.f.FVT[el][0][48 + b] = rh1*v2 - rh2*v1;           // cr
            s_p.f.FVT[el][1][48 + b] = rh2*v0 - rh0*v2;
            s_p.f.FVT[el][2][48 + b] = rh0*v1 - rh1*v0;
        }
        {
            const int b = sub;
            const float d0 = xd_g[(n*16+b)*9+0], d1 = xd_g[(n*16+b)*9+1], d2 = xd_g[(n*16+b)*9+2];
            const float d3 = xd_g[(n*16+b)*9+3], d4 = xd_g[(n*16+b)*9+4], d5 = xd_g[(n*16+b)*9+5];
            const float d6 = xd_g[(n*16+b)*9+6], d7 = xd_g[(n*16+b)*9+7], d8 = xd_g[(n*16+b)*9+8];
            s_FDT[el][0][b]=d0; s_FDT[el][1][b]=d1; s_FDT[el][2][b]=d2;
            s_FDT[el][3][b]=d3; s_FDT[el][4][b]=d4; s_FDT[el][5][b]=d5;
            s_FDT[el][6][b]=d6; s_FDT[el][7][b]=d7; s_FDT[el][8][b]=d8;
            const float uv0 = d0*rh0 + d1*rh1 + d2*rh2;
            const float uv1 = d3*rh0 + d4*rh1 + d5*rh2;
            const float uv2 = d6*rh0 + d7*rh1 + d8*rh2;
            s_p.f.FVT[el][0][32 + b] = uv0;
            s_p.f.FVT[el][1][32 + b] = uv1;
            s_p.f.FVT[el][2][32 + b] = uv2;
            s_p.f.FVT[el][0][80 + b] = rh0*d0 + rh1*d3 + rh2*d6;  // wd
            s_p.f.FVT[el][1][80 + b] = rh0*d1 + rh1*d4 + rh2*d7;
            s_p.f.FVT[el][2][80 + b] = rh0*d2 + rh1*d5 + rh2*d8;
            s_p.f.FS[el][96 + b] = rh0*uv0 + rh1*uv1 + rh2*uv2;   // sd
        }
    }
    __syncthreads();

    // ---- GEMM phase: rad vector in registers, 1-dword A-builds ----
    f32x8 radv;
    #pragma unroll
    for (int l = 0; l < 8; ++l) radv[l] = s_rad[col][l];
    const int r0 = quad*4;
    f32x4 R0={0,0,0,0}, R1={0,0,0,0}, R2={0,0,0,0}, R3={0,0,0,0};
    f32x4 R4={0,0,0,0}, R5={0,0,0,0}, R6={0,0,0,0}, R7={0,0,0,0};

    if (wid == 0) {
        // z_A x {m_a tiles 0-3} -> R0-3; GEMM3 ij 0-3 -> R4-7
        const float* frow = &s_p.f.FS[col][0];
        for (int kk = 0; kk < 28; ++kk) {
            short8 a = build2(radv, frow[kk*4 + quad]);
            const short8* bp = B1 + (kk*7)*64 + lane;
            R0 = MFMA(a, bp[0*64], R0);
            R1 = MFMA(a, bp[1*64], R1);
            R2 = MFMA(a, bp[2*64], R2);
            R3 = MFMA(a, bp[3*64], R3);
        }
        #pragma unroll
        for (int kk = 0; kk < 4; ++kk) {
            const int kq = kk*4 + quad;
            const short8 b3 = B3[kk*64 + lane];
            R4 = MFMA(build2(radv, s_FDT[col][0][kq]), b3, R4);
            R5 = MFMA(build2(radv, s_FDT[col][1][kq]), b3, R5);
            R6 = MFMA(build2(radv, s_FDT[col][2][kq]), b3, R6);
            R7 = MFMA(build2(radv, s_FDT[col][3][kq]), b3, R7);
        }
    } else if (wid == 1) {
        // z_A x {as0 t4,t5; a00 t6} -> R0-2; GEMM3 ij 4-8 -> R3-7
        const float* frow = &s_p.f.FS[col][0];
        for (int kk = 0; kk < 28; ++kk) {
            short8 a = build2(radv, frow[kk*4 + quad]);
            const short8* bp = B1 + (kk*7)*64 + lane;
            R0 = MFMA(a, bp[4*64], R0);
            R1 = MFMA(a, bp[5*64], R1);
            R2 = MFMA(a, bp[6*64], R2);
        }
        #pragma unroll
        for (int kk = 0; kk < 4; ++kk) {
            const int kq = kk*4 + quad;
            const short8 b3 = B3[kk*64 + lane];
            R3 = MFMA(build2(radv, s_FDT[col][4][kq]), b3, R3);
            R4 = MFMA(build2(radv, s_FDT[col][5][kq]), b3, R4);
            R5 = MFMA(build2(radv, s_FDT[col][6][kq]), b3, R5);
            R6 = MFMA(build2(radv, s_FDT[col][7][kq]), b3, R6);
            R7 = MFMA(build2(radv, s_FDT[col][8][kq]), b3, R7);
        }
    } else if (wid == 2) {
        // z_V^0 x {av0 t0,t1; aj0 t2} -> R0,R1,R2; z_V^1 x {av1 t0,t1} -> R3,R4
        const float* f0 = &s_p.f.FVT[col][0][0];
        const float* f1 = &s_p.f.FVT[col][1][0];
        for (int kk = 0; kk < 24; ++kk) {
            const int kq = kk*4 + quad;
            short8 a0 = build2(radv, f0[kq]);
            short8 a1 = build2(radv, f1[kq]);
            const short8* bp = B2 + (kk*3)*64 + lane;
            short8 b0 = bp[0*64], b1 = bp[1*64], b2 = bp[2*64];
            R0 = MFMA(a0, b0, R0);
            R1 = MFMA(a0, b1, R1);
            R2 = MFMA(a0, b2, R2);
            R3 = MFMA(a1, b0, R3);
            R4 = MFMA(a1, b1, R4);
        }
    } else {
        // z_V^1 x {aj1 t2} -> R0; z_V^2 x {av2 t0,t1; aj2 t2} -> R1,R2,R3
        const float* f1 = &s_p.f.FVT[col][1][0];
        const float* f2 = &s_p.f.FVT[col][2][0];
        for (int kk = 0; kk < 24; ++kk) {
            const int kq = kk*4 + quad;
            short8 a1 = build2(radv, f1[kq]);
            short8 a2 = build2(radv, f2[kq]);
            const short8* bp = B2 + (kk*3)*64 + lane;
            short8 b0 = bp[0*64], b1 = bp[1*64], b2 = bp[2*64];
            R0 = MFMA(a1, b2, R0);
            R1 = MFMA(a2, b0, R1);
            R2 = MFMA(a2, b1, R2);
            R3 = MFMA(a2, b2, R3);
        }
    }
    __syncthreads();   // feature pool retires; g (aliased) becomes writable

    // ---- spill results to (unioned) staging ----
    if (wid == 0) {
        #pragma unroll
        for (int r = 0; r < 4; ++r) {
            s_p.g.m[r0+r][ 0+col] = R0[r];
            s_p.g.m[r0+r][16+col] = R1[r];
            s_p.g.m[r0+r][32+col] = R2[r];
            s_p.g.m[r0+r][48+col] = R3[r];
            s_p.g.m[r0+r][160 + col*9 + 0] = R4[r];
            s_p.g.m[r0+r][160 + col*9 + 1] = R5[r];
            s_p.g.m[r0+r][160 + col*9 + 2] = R6[r];
            s_p.g.m[r0+r][160 + col*9 + 3] = R7[r];
        }
    } else if (wid == 1) {
        #pragma unroll
        for (int r = 0; r < 4; ++r) {
            s_p.g.as0[r0+r][ 0+col] = R0[r];
            s_p.g.as0[r0+r][16+col] = R1[r];
            s_p.g.a00[r0+r][col]    = R2[r];
            s_p.g.m[r0+r][160 + col*9 + 4] = R3[r];
            s_p.g.m[r0+r][160 + col*9 + 5] = R4[r];
            s_p.g.m[r0+r][160 + col*9 + 6] = R5[r];
            s_p.g.m[r0+r][160 + col*9 + 7] = R6[r];
            s_p.g.m[r0+r][160 + col*9 + 8] = R7[r];
        }
    } else if (wid == 2) {
        #pragma unroll
        for (int r = 0; r < 4; ++r) {
            s_p.g.m[r0+r][64 + ( 0+col)*3 + 0] = R0[r];
            s_p.g.m[r0+r][64 + (16+col)*3 + 0] = R1[r];
            s_p.g.aj[r0+r][0][col]             = R2[r];
            s_p.g.m[r0+r][64 + ( 0+col)*3 + 1] = R3[r];
            s_p.g.m[r0+r][64 + (16+col)*3 + 1] = R4[r];
        }
    } else {
        #pragma unroll
        for (int r = 0; r < 4; ++r) {
            s_p.g.aj[r0+r][1][col]             = R0[r];
            s_p.g.m[r0+r][64 + ( 0+col)*3 + 2] = R1[r];
            s_p.g.m[r0+r][64 + (16+col)*3 + 2] = R2[r];
            s_p.g.aj[r0+r][2][col]             = R3[r];
        }
    }
    __syncthreads();

    // ---- combine: recouple rh factors ----
    #pragma unroll
    for (int it = t; it < EB*32; it += NTHREADS) {
        const int el = it >> 5, c = it & 31;
        const float as0 = s_p.g.as0[el][c];
        s_p.g.m[el][64 + c*3 + 0] += s_rh[el][0]*as0;
        s_p.g.m[el][64 + c*3 + 1] += s_rh[el][1]*as0;
        s_p.g.m[el][64 + c*3 + 2] += s_rh[el][2]*as0;
    }
    {
        const int el = t >> 4, c = t & 15;
        const float a00 = s_p.g.a00[el][c];
        const float aj0 = s_p.g.aj[el][0][c], aj1 = s_p.g.aj[el][1][c], aj2 = s_p.g.aj[el][2][c];
        const float rr0 = s_rh[el][0], rr1 = s_rh[el][1], rr2 = s_rh[el][2];
        const float g0 = aj0 + rr0*a00, g1 = aj1 + rr1*a00, g2 = aj2 + rr2*a00;
        float* md = &s_p.g.m[el][160 + c*9];
        md[0] += rr0*g0; md[1] += rr0*g1; md[2] += rr0*g2;
        md[3] += rr1*g0; md[4] += rr1*g1; md[5] += rr1*g2;
        md[6] += rr2*g0; md[7] += rr2*g1; md[8] += rr2*g2;
    }
    __syncthreads();

    // ---- segmented emit: s_dst non-decreasing -> one atomic per (segment, channel) ----
    for (int ch = t; ch < OUT_CH; ch += NTHREADS) {
        float run = 0.0f;
        #pragma unroll
        for (int el = 0; el < EB; ++el) {
            run += s_p.g.m[el][ch];
            if (el == EB-1 || s_dst[el+1] != s_dst[el]) {
                atomicAdd(&out[(size_t)s_dst[el]*OUT_CH + ch], run);
                run = 0.0f;
            }
        }
    }
}

extern "C" void kernel_launch(void* const* d_in, const int* in_sizes, int n_in,
                              void* d_out, int out_size, void* d_ws, size_t ws_size,
                              hipStream_t stream)
{
    const float* xa  = (const float*)d_in[0];
    const float* xv  = (const float*)d_in[1];
    const float* xd  = (const float*)d_in[2];
    const float* rij = (const float*)d_in[3];
    const float* P000 = (const float*)d_in[4];
    const float* P110 = (const float*)d_in[5];
    const float* P220 = (const float*)d_in[6];
    const float* P011 = (const float*)d_in[7];
    const float* P101 = (const float*)d_in[8];
    const float* P121 = (const float*)d_in[9];
    const float* P211 = (const float*)d_in[10];
    const float* P111 = (const float*)d_in[11];
    const float* P022 = (const float*)d_in[12];
    const float* P112 = (const float*)d_in[13];
    const float* P202 = (const float*)d_in[14];
    const float* P222 = (const float*)d_in[15];
    const float* P212 = (const float*)d_in[16];
    const int* src = (const int*)d_in[17];
    const int* dst = (const int*)d_in[18];

    unsigned short* BP = (unsigned short*)d_ws;
    int* ip     = (int*)d_ws + (NPACK/2);
    int* cnt    = ip;
    int* off    = ip + NODES;
    int* cursor = off + NODES + 1;
    int* eidx   = cursor + NODES;

    hipMemsetAsync(cnt, 0, NODES * sizeof(int), stream);
    hipMemsetAsync(d_out, 0, (size_t)out_size * sizeof(float), stream);

    prep_kernel<<<EDGES/256, 256, 0, stream>>>(
        P000, P110, P220, P011, P101, P121, P211, P111,
        P022, P112, P202, P222, P212, BP, dst, cnt);
    scan_kernel   <<<1,         256, 0, stream>>>(cnt, off, cursor);
    scatter_kernel<<<EDGES/256, 256, 0, stream>>>(dst, cursor, eidx);

    edge_kernel<<<EDGES/EB, NTHREADS, 0, stream>>>(
        xa, xv, xd, rij, BP, src, dst, eidx, (float*)d_out);
}